// Round 1
// baseline (1224.997 us; speedup 1.0000x reference)
//
#include <hip/hip_runtime.h>
#include <math.h>

#define NN 100000
#define NE 1000000

__device__ __forceinline__ float lrelu(float x, float sl){ return x >= 0.f ? x : sl*x; }

__device__ __forceinline__ void atomicMaxF(float* a, float v){
    if (v >= 0.f) atomicMax((int*)a, __float_as_int(v));
    else          atomicMin((unsigned int*)a, __float_as_uint(v));
}

__global__ void kInitOut(float* out){ out[0] = -INFINITY; }

// Node kernel: ft = hin@Wfc, el/er = head-dots, zero rst, init m/s, compute ce.
template<int DIN, int D, bool MEAN>
__global__ void __launch_bounds__(256) kA(const float* __restrict__ hin,
    const float* __restrict__ Wfc, const float* __restrict__ al,
    const float* __restrict__ ar, const float* __restrict__ We,
    const float* __restrict__ ae,
    float* __restrict__ ft, float* __restrict__ el, float* __restrict__ er,
    float* __restrict__ rst, float* __restrict__ m, float* __restrict__ s,
    float* __restrict__ ce)
{
    const int W = 3*D;
    int n = blockIdx.x*256 + threadIdx.x;
    if (blockIdx.x == 0 && threadIdx.x < 3) {
        float c = 0.f;
        #pragma unroll
        for (int d = 0; d < D; ++d) c += We[threadIdx.x*D+d]*ae[threadIdx.x*D+d];
        ce[threadIdx.x] = c;
    }
    if (n >= NN) return;
    float h[DIN];
    if (MEAN) {
        const float* p = hin + (size_t)n*3*DIN;
        #pragma unroll
        for (int k = 0; k < DIN; ++k) h[k] = (p[k] + p[DIN+k] + p[2*DIN+k]) * (1.f/3.f);
    } else {
        #pragma unroll
        for (int k = 0; k < DIN; ++k) h[k] = hin[(size_t)n*DIN + k];
    }
    float elv[3] = {0,0,0}, erv[3] = {0,0,0};
    #pragma unroll
    for (int j = 0; j < W; ++j) {
        float f = 0.f;
        #pragma unroll
        for (int k = 0; k < DIN; ++k) f += h[k]*Wfc[k*W + j];
        ft[(size_t)n*W + j] = f;
        int hh = j / D;
        elv[hh] += f*al[j];
        erv[hh] += f*ar[j];
        rst[(size_t)n*W + j] = 0.f;
    }
    #pragma unroll
    for (int hh = 0; hh < 3; ++hh) {
        el[n*3+hh] = elv[hh];
        er[n*3+hh] = erv[hh];
        m [n*3+hh] = -INFINITY;
        s [n*3+hh] = 0.f;
    }
}

// Edge pass 1: raw attention logit + segment max into m.
__global__ void __launch_bounds__(256) kB1(const int* __restrict__ src,
    const int* __restrict__ dst, const float* __restrict__ ef,
    const float* __restrict__ el, const float* __restrict__ er,
    const float* __restrict__ ce, float* __restrict__ ebuf, float* __restrict__ m)
{
    int t = blockIdx.x*256 + threadIdx.x;
    if (t >= NE*3) return;
    int e = t/3, h = t - e*3;
    int sN = src[e], dN = dst[e];
    float v = el[sN*3+h] + er[dN*3+h] + ef[e]*ce[h];
    v = lrelu(v, 0.2f);
    ebuf[t] = v;
    atomicMaxF(m + dN*3 + h, v);
}

// Edge pass 2: ex = exp(t - m[dst]); segment sum into s.
__global__ void __launch_bounds__(256) kB2(const int* __restrict__ dst,
    float* __restrict__ ebuf, const float* __restrict__ m, float* __restrict__ s)
{
    int t = blockIdx.x*256 + threadIdx.x;
    if (t >= NE*3) return;
    int e = t/3, h = t - e*3;
    int dN = dst[e];
    float ex = expf(ebuf[t] - m[dN*3+h]);
    ebuf[t] = ex;
    atomicAdd(s + dN*3 + h, ex);
}

// Edge pass 3: rst[dst] += ex * ft[src], element-parallel.
template<int D>
__global__ void __launch_bounds__(256) kC(const int* __restrict__ src,
    const int* __restrict__ dst, const float* __restrict__ ebuf,
    const float* __restrict__ ft, float* __restrict__ rst)
{
    const int W = 3*D;
    int t = blockIdx.x*256 + threadIdx.x;
    if (t >= NE*W) return;
    int e = t / W;
    int j = t - e*W;
    int h = j / D;
    float v = ebuf[e*3 + h] * ft[(size_t)src[e]*W + j];
    atomicAdd(rst + (size_t)dst[e]*W + j, v);
}

// Node finalize: hout = rst/s + hin@Wres + b (in place on rst).
template<int DIN, int D, bool MEAN>
__global__ void __launch_bounds__(256) kD(const float* __restrict__ hin,
    const float* __restrict__ Wr, const float* __restrict__ b,
    const float* __restrict__ s, float* __restrict__ rst)
{
    const int W = 3*D;
    int t = blockIdx.x*256 + threadIdx.x;
    if (t >= NN*W) return;
    int n = t / W;
    int j = t - n*W;
    int h = j / D;
    float res = 0.f;
    #pragma unroll
    for (int k = 0; k < DIN; ++k) {
        float hv;
        if (MEAN) {
            const float* p = hin + (size_t)n*3*DIN;
            hv = (p[k] + p[DIN+k] + p[2*DIN+k]) * (1.f/3.f);
        } else hv = hin[(size_t)n*DIN + k];
        res += hv*Wr[k*W + j];
    }
    float sv = s[n*3 + h];
    float inv = sv > 0.f ? 1.f/sv : 0.f;
    rst[t] = rst[t]*inv + res + b[j];
}

// MLP head + global max.
__global__ void __launch_bounds__(256) kHead(const float* __restrict__ h3,
    const float* __restrict__ L1a_w, const float* __restrict__ L1a_b,
    const float* __restrict__ L1b_w, const float* __restrict__ L1b_b,
    const float* __restrict__ L1c_w, const float* __restrict__ L1c_b,
    const float* __restrict__ L2_w, const float* __restrict__ L2_b,
    float* __restrict__ out)
{
    __shared__ float red[256];
    int n = blockIdx.x*256 + threadIdx.x;
    float y = -INFINITY;
    if (n < NN) {
        const float* p = h3 + (size_t)n*96;
        float acc = L2_b[0];
        #pragma unroll
        for (int h = 0; h < 3; ++h) {
            float x1[16];
            #pragma unroll
            for (int i = 0; i < 16; ++i) {
                float v = L1a_b[i];
                #pragma unroll
                for (int d = 0; d < 32; ++d) v += p[h*32+d]*L1a_w[d*16+i];
                x1[i] = lrelu(v, 0.01f);
            }
            float x2[4];
            #pragma unroll
            for (int i = 0; i < 4; ++i) {
                float v = L1b_b[i];
                #pragma unroll
                for (int d = 0; d < 16; ++d) v += x1[d]*L1b_w[d*4+i];
                x2[i] = lrelu(v, 0.01f);
            }
            float v = L1c_b[0];
            #pragma unroll
            for (int d = 0; d < 4; ++d) v += x2[d]*L1c_w[d];
            acc += v*L2_w[h];
        }
        y = acc;
    }
    red[threadIdx.x] = y;
    __syncthreads();
    for (int o = 128; o > 0; o >>= 1) {
        if (threadIdx.x < o) red[threadIdx.x] = fmaxf(red[threadIdx.x], red[threadIdx.x+o]);
        __syncthreads();
    }
    if (threadIdx.x == 0) atomicMaxF(out, red[0]);
}

extern "C" void kernel_launch(void* const* d_in, const int* in_sizes, int n_in,
                              void* d_out, int out_size, void* d_ws, size_t ws_size,
                              hipStream_t stream) {
    const float* nf  = (const float*)d_in[0];
    const float* ef  = (const float*)d_in[1];
    const float* W1  = (const float*)d_in[2];
    const float* We1 = (const float*)d_in[3];
    const float* al1 = (const float*)d_in[4];
    const float* ar1 = (const float*)d_in[5];
    const float* ae1 = (const float*)d_in[6];
    const float* Wr1 = (const float*)d_in[7];
    const float* b1  = (const float*)d_in[8];
    const float* W2  = (const float*)d_in[9];
    const float* We2 = (const float*)d_in[10];
    const float* al2 = (const float*)d_in[11];
    const float* ar2 = (const float*)d_in[12];
    const float* ae2 = (const float*)d_in[13];
    const float* Wr2 = (const float*)d_in[14];
    const float* b2  = (const float*)d_in[15];
    const float* W3  = (const float*)d_in[16];
    const float* We3 = (const float*)d_in[17];
    const float* al3 = (const float*)d_in[18];
    const float* ar3 = (const float*)d_in[19];
    const float* ae3 = (const float*)d_in[20];
    const float* Wr3 = (const float*)d_in[21];
    const float* b3  = (const float*)d_in[22];
    const float* L1a_w = (const float*)d_in[23];
    const float* L1a_b = (const float*)d_in[24];
    const float* L1b_w = (const float*)d_in[25];
    const float* L1b_b = (const float*)d_in[26];
    const float* L1c_w = (const float*)d_in[27];
    const float* L1c_b = (const float*)d_in[28];
    const float* L2_w  = (const float*)d_in[29];
    const float* L2_b  = (const float*)d_in[30];
    const int* src = (const int*)d_in[31];
    const int* dst = (const int*)d_in[32];
    float* out = (float*)d_out;

    float* ws   = (float*)d_ws;
    float* bufA = ws;                        // [N,96] ft
    float* bufB = bufA + (size_t)NN*96;      // [N,96] rst/hout L1, L3
    float* bufC = bufB + (size_t)NN*96;      // [N,48] rst/hout L2
    float* el   = bufC + (size_t)NN*48;
    float* er   = el + (size_t)NN*3;
    float* m_   = er + (size_t)NN*3;
    float* s_   = m_ + (size_t)NN*3;
    float* ebuf = s_ + (size_t)NN*3;         // [E,3]
    float* ce   = ebuf + (size_t)NE*3;       // [3]

    const int gN  = (NN + 255)/256;
    const int gE3 = (NE*3 + 255)/256;

    kInitOut<<<1,1,0,stream>>>(out);

    // ---- Layer 1: din=6, D=8 ----
    kA<6,8,false><<<gN,256,0,stream>>>(nf, W1, al1, ar1, We1, ae1, bufA, el, er, bufB, m_, s_, ce);
    kB1<<<gE3,256,0,stream>>>(src, dst, ef, el, er, ce, ebuf, m_);
    kB2<<<gE3,256,0,stream>>>(dst, ebuf, m_, s_);
    kC<8><<<(NE*24 + 255)/256,256,0,stream>>>(src, dst, ebuf, bufA, bufB);
    kD<6,8,false><<<(NN*24 + 255)/256,256,0,stream>>>(nf, Wr1, b1, s_, bufB);

    // ---- Layer 2: din=8, D=16 ----
    kA<8,16,true><<<gN,256,0,stream>>>(bufB, W2, al2, ar2, We2, ae2, bufA, el, er, bufC, m_, s_, ce);
    kB1<<<gE3,256,0,stream>>>(src, dst, ef, el, er, ce, ebuf, m_);
    kB2<<<gE3,256,0,stream>>>(dst, ebuf, m_, s_);
    kC<16><<<(NE*48 + 255)/256,256,0,stream>>>(src, dst, ebuf, bufA, bufC);
    kD<8,16,true><<<(NN*48 + 255)/256,256,0,stream>>>(bufB, Wr2, b2, s_, bufC);

    // ---- Layer 3: din=16, D=32 ----
    kA<16,32,true><<<gN,256,0,stream>>>(bufC, W3, al3, ar3, We3, ae3, bufA, el, er, bufB, m_, s_, ce);
    kB1<<<gE3,256,0,stream>>>(src, dst, ef, el, er, ce, ebuf, m_);
    kB2<<<gE3,256,0,stream>>>(dst, ebuf, m_, s_);
    kC<32><<<(NE*96 + 255)/256,256,0,stream>>>(src, dst, ebuf, bufA, bufB);
    kD<16,32,true><<<(NN*96 + 255)/256,256,0,stream>>>(bufC, Wr3, b3, s_, bufB);

    // ---- MLP head + global max ----
    kHead<<<gN,256,0,stream>>>(bufB, L1a_w, L1a_b, L1b_w, L1b_b, L1c_w, L1c_b, L2_w, L2_b, out);
}

// Round 2
// 505.636 us; speedup vs baseline: 2.4227x; 2.4227x over previous
//
#include <hip/hip_runtime.h>
#include <math.h>

#define NN 100000
#define NE 1000000
#define NB_SCAN ((NN + 255) / 256)   // 391

__device__ __forceinline__ float lrelu(float x, float sl){ return x >= 0.f ? x : sl*x; }

__device__ __forceinline__ void atomicMaxF(float* a, float v){
    if (v >= 0.f) atomicMax((int*)a, __float_as_int(v));
    else          atomicMin((unsigned int*)a, __float_as_uint(v));
}

__global__ void kInitOut(float* out){ out[0] = -INFINITY; }

// ---------------- CSR build ----------------
__global__ void __launch_bounds__(256) kHist(const int* __restrict__ dst, int* __restrict__ deg){
    int e = blockIdx.x*256 + threadIdx.x;
    if (e < NE) atomicAdd(&deg[dst[e]], 1);
}

__global__ void __launch_bounds__(256) kScan1(const int* __restrict__ deg,
                                              int* __restrict__ pre, int* __restrict__ bsum){
    __shared__ int sh[256];
    int i = blockIdx.x*256 + threadIdx.x;
    int v = (i < NN) ? deg[i] : 0;
    sh[threadIdx.x] = v;
    __syncthreads();
    for (int o = 1; o < 256; o <<= 1) {
        int t = (threadIdx.x >= o) ? sh[threadIdx.x - o] : 0;
        __syncthreads();
        sh[threadIdx.x] += t;
        __syncthreads();
    }
    if (i < NN) pre[i] = sh[threadIdx.x] - v;   // exclusive
    if (threadIdx.x == 255) bsum[blockIdx.x] = sh[255];
}

__global__ void __launch_bounds__(512) kScan2(int* __restrict__ bsum){
    __shared__ int sh[512];
    int v = (threadIdx.x < NB_SCAN) ? bsum[threadIdx.x] : 0;
    sh[threadIdx.x] = v;
    __syncthreads();
    for (int o = 1; o < 512; o <<= 1) {
        int t = (threadIdx.x >= o) ? sh[threadIdx.x - o] : 0;
        __syncthreads();
        sh[threadIdx.x] += t;
        __syncthreads();
    }
    if (threadIdx.x < NB_SCAN) bsum[threadIdx.x] = sh[threadIdx.x] - v;  // exclusive
}

__global__ void __launch_bounds__(256) kScanFin(int* __restrict__ pre, const int* __restrict__ bsum,
                                                int* __restrict__ cur){
    int i = blockIdx.x*256 + threadIdx.x;
    if (i >= NN) return;
    int v = pre[i] + bsum[blockIdx.x];
    pre[i] = v;
    cur[i] = v;
}

__global__ void __launch_bounds__(256) kScatter(const int* __restrict__ src, const int* __restrict__ dst,
                                                const float* __restrict__ ef,
                                                int* __restrict__ cur,
                                                int* __restrict__ csr_src, float* __restrict__ csr_ef){
    int e = blockIdx.x*256 + threadIdx.x;
    if (e >= NE) return;
    int pos = atomicAdd(&cur[dst[e]], 1);
    csr_src[pos] = src[e];
    csr_ef[pos]  = ef[e];
}
// after kScatter: cur[n] == row-end of node n

// ---------------- per-layer kernels ----------------
template<int DIN, int D, bool MEAN>
__global__ void __launch_bounds__(256) kA(const float* __restrict__ hin,
    const float* __restrict__ Wfc, const float* __restrict__ al,
    const float* __restrict__ ar, const float* __restrict__ We,
    const float* __restrict__ ae,
    float* __restrict__ ft, float* __restrict__ el, float* __restrict__ er,
    float* __restrict__ ce)
{
    const int W = 3*D;
    int n = blockIdx.x*256 + threadIdx.x;
    if (blockIdx.x == 0 && threadIdx.x < 3) {
        float c = 0.f;
        #pragma unroll
        for (int d = 0; d < D; ++d) c += We[threadIdx.x*D+d]*ae[threadIdx.x*D+d];
        ce[threadIdx.x] = c;
    }
    if (n >= NN) return;
    float h[DIN];
    if (MEAN) {
        const float* p = hin + (size_t)n*3*DIN;
        #pragma unroll
        for (int k = 0; k < DIN; ++k) h[k] = (p[k] + p[DIN+k] + p[2*DIN+k]) * (1.f/3.f);
    } else {
        #pragma unroll
        for (int k = 0; k < DIN; ++k) h[k] = hin[(size_t)n*DIN + k];
    }
    float elv[3] = {0,0,0}, erv[3] = {0,0,0};
    #pragma unroll
    for (int j = 0; j < W; ++j) {
        float f = 0.f;
        #pragma unroll
        for (int k = 0; k < DIN; ++k) f += h[k]*Wfc[k*W + j];
        ft[(size_t)n*W + j] = f;
        int hh = j / D;
        elv[hh] += f*al[j];
        erv[hh] += f*ar[j];
    }
    #pragma unroll
    for (int hh = 0; hh < 3; ++hh) {
        el[n*3+hh] = elv[hh];
        er[n*3+hh] = erv[hh];
    }
}

__global__ void __launch_bounds__(256) kSM(const int* __restrict__ row, const int* __restrict__ rend,
    const int* __restrict__ csr_src, const float* __restrict__ csr_ef,
    const float* __restrict__ el, const float* __restrict__ er,
    const float* __restrict__ ce,
    float* __restrict__ ebuf, float* __restrict__ sinv)
{
    int n = blockIdx.x*256 + threadIdx.x;
    if (n >= NN) return;
    int rs = row[n], re = rend[n];
    float c0 = ce[0], c1 = ce[1], c2 = ce[2];
    float e0 = er[n*3+0], e1 = er[n*3+1], e2 = er[n*3+2];
    float m0 = -INFINITY, m1 = -INFINITY, m2 = -INFINITY;
    for (int p = rs; p < re; ++p) {
        int sv = csr_src[p];
        float fv = csr_ef[p];
        float v0 = lrelu(el[sv*3+0] + e0 + c0*fv, 0.2f);
        float v1 = lrelu(el[sv*3+1] + e1 + c1*fv, 0.2f);
        float v2 = lrelu(el[sv*3+2] + e2 + c2*fv, 0.2f);
        ebuf[p*3+0] = v0; ebuf[p*3+1] = v1; ebuf[p*3+2] = v2;
        m0 = fmaxf(m0, v0); m1 = fmaxf(m1, v1); m2 = fmaxf(m2, v2);
    }
    float s0 = 0.f, s1 = 0.f, s2 = 0.f;
    for (int p = rs; p < re; ++p) {
        float x0 = expf(ebuf[p*3+0] - m0);
        float x1 = expf(ebuf[p*3+1] - m1);
        float x2 = expf(ebuf[p*3+2] - m2);
        ebuf[p*3+0] = x0; ebuf[p*3+1] = x1; ebuf[p*3+2] = x2;
        s0 += x0; s1 += x1; s2 += x2;
    }
    sinv[n*3+0] = s0 > 0.f ? 1.f/s0 : 0.f;
    sinv[n*3+1] = s1 > 0.f ? 1.f/s1 : 0.f;
    sinv[n*3+2] = s2 > 0.f ? 1.f/s2 : 0.f;
}

template<int DIN, int D, bool MEAN>
__global__ void __launch_bounds__(256) kAgg(const int* __restrict__ row, const int* __restrict__ rend,
    const int* __restrict__ csr_src, const float* __restrict__ ebuf,
    const float* __restrict__ ft, const float* __restrict__ sinv,
    const float* __restrict__ hin, const float* __restrict__ Wr,
    const float* __restrict__ b, float* __restrict__ hout)
{
    const int W = 3*D;
    const int T = W/4;
    int t = blockIdx.x*256 + threadIdx.x;
    if (t >= NN*T) return;
    int n = t / T;
    int lane = t - n*T;
    int h = (lane*4) / D;

    const float4* ftv = (const float4*)ft;
    int rs = row[n], re = rend[n];
    float4 acc = make_float4(0.f, 0.f, 0.f, 0.f);
    for (int p = rs; p < re; ++p) {
        int sv = csr_src[p];
        float a = ebuf[p*3 + h];
        float4 f = ftv[(size_t)sv*T + lane];
        acc.x += a*f.x; acc.y += a*f.y; acc.z += a*f.z; acc.w += a*f.w;
    }
    float inv = sinv[n*3 + h];

    float hv[DIN];
    if (MEAN) {
        const float* p = hin + (size_t)n*3*DIN;
        #pragma unroll
        for (int k = 0; k < DIN; ++k) hv[k] = (p[k] + p[DIN+k] + p[2*DIN+k]) * (1.f/3.f);
    } else {
        #pragma unroll
        for (int k = 0; k < DIN; ++k) hv[k] = hin[(size_t)n*DIN + k];
    }
    const float4* Wrv = (const float4*)Wr;
    float4 res = ((const float4*)b)[lane];
    #pragma unroll
    for (int k = 0; k < DIN; ++k) {
        float4 w = Wrv[k*T + lane];
        res.x += hv[k]*w.x; res.y += hv[k]*w.y; res.z += hv[k]*w.z; res.w += hv[k]*w.w;
    }
    float4 o;
    o.x = acc.x*inv + res.x;
    o.y = acc.y*inv + res.y;
    o.z = acc.z*inv + res.z;
    o.w = acc.w*inv + res.w;
    ((float4*)hout)[(size_t)n*T + lane] = o;
}

__global__ void __launch_bounds__(256) kHead(const float* __restrict__ h3,
    const float* __restrict__ L1a_w, const float* __restrict__ L1a_b,
    const float* __restrict__ L1b_w, const float* __restrict__ L1b_b,
    const float* __restrict__ L1c_w, const float* __restrict__ L1c_b,
    const float* __restrict__ L2_w, const float* __restrict__ L2_b,
    float* __restrict__ out)
{
    __shared__ float red[256];
    int n = blockIdx.x*256 + threadIdx.x;
    float y = -INFINITY;
    if (n < NN) {
        const float* p = h3 + (size_t)n*96;
        float acc = L2_b[0];
        #pragma unroll
        for (int h = 0; h < 3; ++h) {
            float x1[16];
            #pragma unroll
            for (int i = 0; i < 16; ++i) {
                float v = L1a_b[i];
                #pragma unroll
                for (int d = 0; d < 32; ++d) v += p[h*32+d]*L1a_w[d*16+i];
                x1[i] = lrelu(v, 0.01f);
            }
            float x2[4];
            #pragma unroll
            for (int i = 0; i < 4; ++i) {
                float v = L1b_b[i];
                #pragma unroll
                for (int d = 0; d < 16; ++d) v += x1[d]*L1b_w[d*4+i];
                x2[i] = lrelu(v, 0.01f);
            }
            float v = L1c_b[0];
            #pragma unroll
            for (int d = 0; d < 4; ++d) v += x2[d]*L1c_w[d];
            acc += v*L2_w[h];
        }
        y = acc;
    }
    red[threadIdx.x] = y;
    __syncthreads();
    for (int o = 128; o > 0; o >>= 1) {
        if (threadIdx.x < o) red[threadIdx.x] = fmaxf(red[threadIdx.x], red[threadIdx.x+o]);
        __syncthreads();
    }
    if (threadIdx.x == 0) atomicMaxF(out, red[0]);
}

extern "C" void kernel_launch(void* const* d_in, const int* in_sizes, int n_in,
                              void* d_out, int out_size, void* d_ws, size_t ws_size,
                              hipStream_t stream) {
    const float* nf  = (const float*)d_in[0];
    const float* ef  = (const float*)d_in[1];
    const float* W1  = (const float*)d_in[2];
    const float* We1 = (const float*)d_in[3];
    const float* al1 = (const float*)d_in[4];
    const float* ar1 = (const float*)d_in[5];
    const float* ae1 = (const float*)d_in[6];
    const float* Wr1 = (const float*)d_in[7];
    const float* b1  = (const float*)d_in[8];
    const float* W2  = (const float*)d_in[9];
    const float* We2 = (const float*)d_in[10];
    const float* al2 = (const float*)d_in[11];
    const float* ar2 = (const float*)d_in[12];
    const float* ae2 = (const float*)d_in[13];
    const float* Wr2 = (const float*)d_in[14];
    const float* b2  = (const float*)d_in[15];
    const float* W3  = (const float*)d_in[16];
    const float* We3 = (const float*)d_in[17];
    const float* al3 = (const float*)d_in[18];
    const float* ar3 = (const float*)d_in[19];
    const float* ae3 = (const float*)d_in[20];
    const float* Wr3 = (const float*)d_in[21];
    const float* b3  = (const float*)d_in[22];
    const float* L1a_w = (const float*)d_in[23];
    const float* L1a_b = (const float*)d_in[24];
    const float* L1b_w = (const float*)d_in[25];
    const float* L1b_b = (const float*)d_in[26];
    const float* L1c_w = (const float*)d_in[27];
    const float* L1c_b = (const float*)d_in[28];
    const float* L2_w  = (const float*)d_in[29];
    const float* L2_b  = (const float*)d_in[30];
    const int* src = (const int*)d_in[31];
    const int* dst = (const int*)d_in[32];
    float* out = (float*)d_out;

    float* ws   = (float*)d_ws;
    float* bufA = ws;                         // ft      [N,96]
    float* bufB = bufA + (size_t)NN*96;       // h L1/L3 [N,96]
    float* bufC = bufB + (size_t)NN*96;       // h L2    [N,48]
    float* el   = bufC + (size_t)NN*48;       // [N,3]
    float* er   = el + (size_t)NN*3;          // [N,3]
    float* sinv = er + (size_t)NN*3;          // [N,3]
    float* ebuf = sinv + (size_t)NN*3;        // [E,3]
    float* ce   = ebuf + (size_t)NE*3;        // [4]
    float* csr_ef = ce + 4;                   // [E]
    int* deg    = (int*)(csr_ef + (size_t)NE);// [N]
    int* pre    = deg + NN;                   // [N] -> row start
    int* cur    = pre + NN;                   // [N] -> row end
    int* bsum   = cur + NN;                   // [512]
    int* csr_src= bsum + 512;                 // [E]

    const int gN  = (NN + 255)/256;
    const int gE  = (NE + 255)/256;

    kInitOut<<<1,1,0,stream>>>(out);

    hipMemsetAsync(deg, 0, NN*sizeof(int), stream);
    kHist<<<gE,256,0,stream>>>(dst, deg);
    kScan1<<<NB_SCAN,256,0,stream>>>(deg, pre, bsum);
    kScan2<<<1,512,0,stream>>>(bsum);
    kScanFin<<<NB_SCAN,256,0,stream>>>(pre, bsum, cur);
    kScatter<<<gE,256,0,stream>>>(src, dst, ef, cur, csr_src, csr_ef);
    int* row  = pre;
    int* rend = cur;

    // ---- Layer 1: din=6, D=8 ----
    kA<6,8,false><<<gN,256,0,stream>>>(nf, W1, al1, ar1, We1, ae1, bufA, el, er, ce);
    kSM<<<gN,256,0,stream>>>(row, rend, csr_src, csr_ef, el, er, ce, ebuf, sinv);
    kAgg<6,8,false><<<(NN*6 + 255)/256,256,0,stream>>>(row, rend, csr_src, ebuf, bufA, sinv, nf, Wr1, b1, bufB);

    // ---- Layer 2: din=8, D=16 ----
    kA<8,16,true><<<gN,256,0,stream>>>(bufB, W2, al2, ar2, We2, ae2, bufA, el, er, ce);
    kSM<<<gN,256,0,stream>>>(row, rend, csr_src, csr_ef, el, er, ce, ebuf, sinv);
    kAgg<8,16,true><<<(NN*12 + 255)/256,256,0,stream>>>(row, rend, csr_src, ebuf, bufA, sinv, bufB, Wr2, b2, bufC);

    // ---- Layer 3: din=16, D=32 ----
    kA<16,32,true><<<gN,256,0,stream>>>(bufC, W3, al3, ar3, We3, ae3, bufA, el, er, ce);
    kSM<<<gN,256,0,stream>>>(row, rend, csr_src, csr_ef, el, er, ce, ebuf, sinv);
    kAgg<16,32,true><<<(NN*24 + 255)/256,256,0,stream>>>(row, rend, csr_src, ebuf, bufA, sinv, bufC, Wr3, b3, bufB);

    kHead<<<gN,256,0,stream>>>(bufB, L1a_w, L1a_b, L1b_w, L1b_b, L1c_w, L1c_b, L2_w, L2_b, out);
}

// Round 3
// 455.182 us; speedup vs baseline: 2.6912x; 1.1108x over previous
//
#include <hip/hip_runtime.h>
#include <hip/hip_fp16.h>
#include <math.h>

#define NN 100000
#define NE 1000000
#define NB_SCAN ((NN + 255) / 256)   // 391
#define CAP 64                       // LDS-cached edges per node (Poisson(10): P(deg>64) ~ 0)

__device__ __forceinline__ float lrelu(float x, float sl){ return x >= 0.f ? x : sl*x; }

__device__ __forceinline__ void atomicMaxF(float* a, float v){
    if (v >= 0.f) atomicMax((int*)a, __float_as_int(v));
    else          atomicMin((unsigned int*)a, __float_as_uint(v));
}

__global__ void kInitOut(float* out){ out[0] = -INFINITY; }

// ---------------- CSR build ----------------
__global__ void __launch_bounds__(256) kHist(const int* __restrict__ dst, int* __restrict__ deg){
    int e = blockIdx.x*256 + threadIdx.x;
    if (e < NE) atomicAdd(&deg[dst[e]], 1);
}

__global__ void __launch_bounds__(256) kScan1(const int* __restrict__ deg,
                                              int* __restrict__ pre, int* __restrict__ bsum){
    __shared__ int sh[256];
    int i = blockIdx.x*256 + threadIdx.x;
    int v = (i < NN) ? deg[i] : 0;
    sh[threadIdx.x] = v;
    __syncthreads();
    for (int o = 1; o < 256; o <<= 1) {
        int t = (threadIdx.x >= o) ? sh[threadIdx.x - o] : 0;
        __syncthreads();
        sh[threadIdx.x] += t;
        __syncthreads();
    }
    if (i < NN) pre[i] = sh[threadIdx.x] - v;   // exclusive
    if (threadIdx.x == 255) bsum[blockIdx.x] = sh[255];
}

__global__ void __launch_bounds__(512) kScan2(int* __restrict__ bsum){
    __shared__ int sh[512];
    int v = (threadIdx.x < NB_SCAN) ? bsum[threadIdx.x] : 0;
    sh[threadIdx.x] = v;
    __syncthreads();
    for (int o = 1; o < 512; o <<= 1) {
        int t = (threadIdx.x >= o) ? sh[threadIdx.x - o] : 0;
        __syncthreads();
        sh[threadIdx.x] += t;
        __syncthreads();
    }
    if (threadIdx.x < NB_SCAN) bsum[threadIdx.x] = sh[threadIdx.x] - v;  // exclusive
}

__global__ void __launch_bounds__(256) kScanFin(int* __restrict__ pre, const int* __restrict__ bsum,
                                                int* __restrict__ cur){
    int i = blockIdx.x*256 + threadIdx.x;
    if (i >= NN) return;
    int v = pre[i] + bsum[blockIdx.x];
    pre[i] = v;
    cur[i] = v;
}

__global__ void __launch_bounds__(256) kScatter(const int* __restrict__ src, const int* __restrict__ dst,
                                                const float* __restrict__ ef,
                                                int* __restrict__ cur,
                                                int* __restrict__ csr_src, float* __restrict__ csr_ef){
    int e = blockIdx.x*256 + threadIdx.x;
    if (e >= NE) return;
    int pos = atomicAdd(&cur[dst[e]], 1);
    csr_src[pos] = src[e];
    csr_ef[pos]  = ef[e];
}
// after kScatter: cur[n] == row-end of node n

// ---------------- node projection ----------------
// ft (fp16) = hin@Wfc; el4[n] = (el0,el1,el2,0); er[n*3]; ce[h] = We_h . ae_h
template<int DIN, int D, bool MEAN>
__global__ void __launch_bounds__(256) kA(const float* __restrict__ hin,
    const float* __restrict__ Wfc, const float* __restrict__ al,
    const float* __restrict__ ar, const float* __restrict__ We,
    const float* __restrict__ ae,
    __half* __restrict__ fth, float4* __restrict__ el4, float* __restrict__ er,
    float* __restrict__ ce)
{
    const int W = 3*D;
    int n = blockIdx.x*256 + threadIdx.x;
    if (blockIdx.x == 0 && threadIdx.x < 3) {
        float c = 0.f;
        #pragma unroll
        for (int d = 0; d < D; ++d) c += We[threadIdx.x*D+d]*ae[threadIdx.x*D+d];
        ce[threadIdx.x] = c;
    }
    if (n >= NN) return;
    float h[DIN];
    if (MEAN) {
        const float* p = hin + (size_t)n*3*DIN;
        #pragma unroll
        for (int k = 0; k < DIN; ++k) h[k] = (p[k] + p[DIN+k] + p[2*DIN+k]) * (1.f/3.f);
    } else {
        #pragma unroll
        for (int k = 0; k < DIN; ++k) h[k] = hin[(size_t)n*DIN + k];
    }
    float elv[3] = {0,0,0}, erv[3] = {0,0,0};
    #pragma unroll
    for (int j = 0; j < W; ++j) {
        float f = 0.f;
        #pragma unroll
        for (int k = 0; k < DIN; ++k) f += h[k]*Wfc[k*W + j];
        fth[(size_t)n*W + j] = __float2half(f);
        int hh = j / D;
        elv[hh] += f*al[j];
        erv[hh] += f*ar[j];
    }
    el4[n] = make_float4(elv[0], elv[1], elv[2], 0.f);
    #pragma unroll
    for (int hh = 0; hh < 3; ++hh) er[n*3+hh] = erv[hh];
}

// ---------------- fused softmax + aggregation + finalize ----------------
// One LANES-group per node. Phase 1: edge-parallel ex=exp(lrelu(logit)) into LDS
// (no max-subtraction: logits are O(1), exactly equivalent in exact arithmetic).
// Phase 2: T=W/4 feature lanes gather fp16 ft[src] and accumulate; finalize with
// 1/s, residual projection, bias.
template<int DIN, int D, int LANES, bool MEAN>
__global__ void __launch_bounds__(256) kFused(
    const int* __restrict__ row, const int* __restrict__ rend,
    const int* __restrict__ csr_src, const float* __restrict__ csr_ef,
    const float4* __restrict__ el4, const float* __restrict__ er,
    const float* __restrict__ ce, const __half* __restrict__ fth,
    const float* __restrict__ hin, const float* __restrict__ Wr,
    const float* __restrict__ b, float* __restrict__ hout,
    float* __restrict__ ovf)
{
    const int W = 3*D, T = W/4;
    const int GP = 256/LANES;
    __shared__ float exs[GP][CAP*3];
    int sub  = threadIdx.x / LANES;
    int lane = threadIdx.x - sub*LANES;
    int n = blockIdx.x*GP + sub;
    bool alive = n < NN;
    int rs = 0, deg = 0;
    if (alive) { rs = row[n]; deg = rend[n] - rs; }
    float c0 = ce[0], c1 = ce[1], c2 = ce[2];
    float e0 = 0.f, e1 = 0.f, e2 = 0.f;
    if (alive) { e0 = er[n*3+0]; e1 = er[n*3+1]; e2 = er[n*3+2]; }

    float s0 = 0.f, s1 = 0.f, s2 = 0.f;
    for (int p0 = lane; p0 < deg; p0 += LANES) {
        int p = rs + p0;
        int sv = csr_src[p];
        float fv = csr_ef[p];
        float4 ev = el4[sv];
        float x0 = expf(lrelu(ev.x + e0 + c0*fv, 0.2f));
        float x1 = expf(lrelu(ev.y + e1 + c1*fv, 0.2f));
        float x2 = expf(lrelu(ev.z + e2 + c2*fv, 0.2f));
        s0 += x0; s1 += x1; s2 += x2;
        if (p0 < CAP) {
            exs[sub][p0*3+0] = x0; exs[sub][p0*3+1] = x1; exs[sub][p0*3+2] = x2;
        } else {
            ovf[(size_t)p*3+0] = x0; ovf[(size_t)p*3+1] = x1; ovf[(size_t)p*3+2] = x2;
        }
    }
    #pragma unroll
    for (int o = LANES/2; o > 0; o >>= 1) {
        s0 += __shfl_xor(s0, o);
        s1 += __shfl_xor(s1, o);
        s2 += __shfl_xor(s2, o);
    }
    __syncthreads();
    if (!alive || lane >= T) return;

    int h = (lane*4)/D;
    float sh = (h == 0) ? s0 : ((h == 1) ? s1 : s2);
    float inv = sh > 0.f ? 1.f/sh : 0.f;

    float4 acc = make_float4(0.f, 0.f, 0.f, 0.f);
    const float2* ftv = (const float2*)fth;
    for (int p0 = 0; p0 < deg; ++p0) {
        float a = (p0 < CAP) ? exs[sub][p0*3+h] : ovf[(size_t)(rs+p0)*3+h];
        int sv = csr_src[rs + p0];
        float2 raw = ftv[(size_t)sv*T + lane];
        __half2 h01 = *(const __half2*)&raw.x;
        __half2 h23 = *(const __half2*)&raw.y;
        float2 f01 = __half22float2(h01);
        float2 f23 = __half22float2(h23);
        acc.x += a*f01.x; acc.y += a*f01.y; acc.z += a*f23.x; acc.w += a*f23.y;
    }

    float hv[DIN];
    if (MEAN) {
        const float* p = hin + (size_t)n*3*DIN;
        #pragma unroll
        for (int k = 0; k < DIN; ++k) hv[k] = (p[k] + p[DIN+k] + p[2*DIN+k]) * (1.f/3.f);
    } else {
        #pragma unroll
        for (int k = 0; k < DIN; ++k) hv[k] = hin[(size_t)n*DIN + k];
    }
    const float4* Wrv = (const float4*)Wr;
    float4 res = ((const float4*)b)[lane];
    #pragma unroll
    for (int k = 0; k < DIN; ++k) {
        float4 w = Wrv[k*T + lane];
        res.x += hv[k]*w.x; res.y += hv[k]*w.y; res.z += hv[k]*w.z; res.w += hv[k]*w.w;
    }
    float4 o;
    o.x = acc.x*inv + res.x;
    o.y = acc.y*inv + res.y;
    o.z = acc.z*inv + res.z;
    o.w = acc.w*inv + res.w;
    ((float4*)hout)[(size_t)n*T + lane] = o;
}

// ---------------- MLP head + global max ----------------
__global__ void __launch_bounds__(256) kHead(const float* __restrict__ h3,
    const float* __restrict__ L1a_w, const float* __restrict__ L1a_b,
    const float* __restrict__ L1b_w, const float* __restrict__ L1b_b,
    const float* __restrict__ L1c_w, const float* __restrict__ L1c_b,
    const float* __restrict__ L2_w, const float* __restrict__ L2_b,
    float* __restrict__ out)
{
    __shared__ float red[256];
    int n = blockIdx.x*256 + threadIdx.x;
    float y = -INFINITY;
    if (n < NN) {
        const float* p = h3 + (size_t)n*96;
        float acc = L2_b[0];
        #pragma unroll
        for (int h = 0; h < 3; ++h) {
            float x1[16];
            #pragma unroll
            for (int i = 0; i < 16; ++i) {
                float v = L1a_b[i];
                #pragma unroll
                for (int d = 0; d < 32; ++d) v += p[h*32+d]*L1a_w[d*16+i];
                x1[i] = lrelu(v, 0.01f);
            }
            float x2[4];
            #pragma unroll
            for (int i = 0; i < 4; ++i) {
                float v = L1b_b[i];
                #pragma unroll
                for (int d = 0; d < 16; ++d) v += x1[d]*L1b_w[d*4+i];
                x2[i] = lrelu(v, 0.01f);
            }
            float v = L1c_b[0];
            #pragma unroll
            for (int d = 0; d < 4; ++d) v += x2[d]*L1c_w[d];
            acc += v*L2_w[h];
        }
        y = acc;
    }
    red[threadIdx.x] = y;
    __syncthreads();
    for (int o = 128; o > 0; o >>= 1) {
        if (threadIdx.x < o) red[threadIdx.x] = fmaxf(red[threadIdx.x], red[threadIdx.x+o]);
        __syncthreads();
    }
    if (threadIdx.x == 0) atomicMaxF(out, red[0]);
}

extern "C" void kernel_launch(void* const* d_in, const int* in_sizes, int n_in,
                              void* d_out, int out_size, void* d_ws, size_t ws_size,
                              hipStream_t stream) {
    const float* nf  = (const float*)d_in[0];
    const float* ef  = (const float*)d_in[1];
    const float* W1  = (const float*)d_in[2];
    const float* We1 = (const float*)d_in[3];
    const float* al1 = (const float*)d_in[4];
    const float* ar1 = (const float*)d_in[5];
    const float* ae1 = (const float*)d_in[6];
    const float* Wr1 = (const float*)d_in[7];
    const float* b1  = (const float*)d_in[8];
    const float* W2  = (const float*)d_in[9];
    const float* We2 = (const float*)d_in[10];
    const float* al2 = (const float*)d_in[11];
    const float* ar2 = (const float*)d_in[12];
    const float* ae2 = (const float*)d_in[13];
    const float* Wr2 = (const float*)d_in[14];
    const float* b2  = (const float*)d_in[15];
    const float* W3  = (const float*)d_in[16];
    const float* We3 = (const float*)d_in[17];
    const float* al3 = (const float*)d_in[18];
    const float* ar3 = (const float*)d_in[19];
    const float* ae3 = (const float*)d_in[20];
    const float* Wr3 = (const float*)d_in[21];
    const float* b3  = (const float*)d_in[22];
    const float* L1a_w = (const float*)d_in[23];
    const float* L1a_b = (const float*)d_in[24];
    const float* L1b_w = (const float*)d_in[25];
    const float* L1b_b = (const float*)d_in[26];
    const float* L1c_w = (const float*)d_in[27];
    const float* L1c_b = (const float*)d_in[28];
    const float* L2_w  = (const float*)d_in[29];
    const float* L2_b  = (const float*)d_in[30];
    const int* src = (const int*)d_in[31];
    const int* dst = (const int*)d_in[32];
    float* out = (float*)d_out;

    float* ws   = (float*)d_ws;
    __half* fth = (__half*)ws;                        // ft fp16 [N,96] = NN*48 floats
    float* bufB = ws + (size_t)NN*48;                 // h L1 [N,24] / L3 out [N,96]
    float* bufC = bufB + (size_t)NN*96;               // h L2 [N,48]
    float4* el4 = (float4*)(bufC + (size_t)NN*48);    // [N] float4
    float* er   = (float*)(el4 + NN);                 // [N,3]
    float* ce   = er + (size_t)NN*3;                  // [4]
    float* csr_ef = ce + 4;                           // [E]
    float* ovf  = csr_ef + (size_t)NE;                // [E,3] overflow ex
    int* deg    = (int*)(ovf + (size_t)NE*3);         // [N]
    int* pre    = deg + NN;                           // [N] -> row start
    int* cur    = pre + NN;                           // [N] -> row end
    int* bsum   = cur + NN;                           // [512]
    int* csr_src= bsum + 512;                         // [E]

    const int gN  = (NN + 255)/256;
    const int gE  = (NE + 255)/256;

    kInitOut<<<1,1,0,stream>>>(out);

    hipMemsetAsync(deg, 0, NN*sizeof(int), stream);
    kHist<<<gE,256,0,stream>>>(dst, deg);
    kScan1<<<NB_SCAN,256,0,stream>>>(deg, pre, bsum);
    kScan2<<<1,512,0,stream>>>(bsum);
    kScanFin<<<NB_SCAN,256,0,stream>>>(pre, bsum, cur);
    kScatter<<<gE,256,0,stream>>>(src, dst, ef, cur, csr_src, csr_ef);
    int* row  = pre;
    int* rend = cur;

    // ---- Layer 1: din=6, D=8, LANES=8 (32 nodes/block) ----
    kA<6,8,false><<<gN,256,0,stream>>>(nf, W1, al1, ar1, We1, ae1, fth, el4, er, ce);
    kFused<6,8,8,false><<<(NN*8 + 255)/256,256,0,stream>>>(row, rend, csr_src, csr_ef,
        el4, er, ce, fth, nf, Wr1, b1, bufB, ovf);

    // ---- Layer 2: din=8, D=16, LANES=16 ----
    kA<8,16,true><<<gN,256,0,stream>>>(bufB, W2, al2, ar2, We2, ae2, fth, el4, er, ce);
    kFused<8,16,16,true><<<(NN*16 + 255)/256,256,0,stream>>>(row, rend, csr_src, csr_ef,
        el4, er, ce, fth, bufB, Wr2, b2, bufC, ovf);

    // ---- Layer 3: din=16, D=32, LANES=32 ----
    kA<16,32,true><<<gN,256,0,stream>>>(bufC, W3, al3, ar3, We3, ae3, fth, el4, er, ce);
    kFused<16,32,32,true><<<(NN*32 + 255)/256,256,0,stream>>>(row, rend, csr_src, csr_ef,
        el4, er, ce, fth, bufC, Wr3, b3, bufB, ovf);

    kHead<<<gN,256,0,stream>>>(bufB, L1a_w, L1a_b, L1b_w, L1b_b, L1c_w, L1c_b, L2_w, L2_b, out);
}

// Round 4
// 345.372 us; speedup vs baseline: 3.5469x; 1.3179x over previous
//
#include <hip/hip_runtime.h>
#include <hip/hip_fp16.h>
#include <math.h>

#define NN 100000
#define NE 1000000
#define NB_SCAN ((NN + 255) / 256)   // 391
#define CAP 64                       // max cached in-edges/node (max observed deg ~30)

typedef unsigned int   u32;
typedef unsigned short u16;

__device__ __forceinline__ float lrelu(float x, float sl){ return x >= 0.f ? x : sl*x; }

__device__ __forceinline__ void atomicMaxF(float* a, float v){
    if (v >= 0.f) atomicMax((int*)a, __float_as_int(v));
    else          atomicMin((unsigned int*)a, __float_as_uint(v));
}

__global__ void kInitOut(float* out){ out[0] = -INFINITY; }

// ---------------- CSR build ----------------
__global__ void __launch_bounds__(256) kHist(const int* __restrict__ dst, int* __restrict__ deg){
    int e = blockIdx.x*256 + threadIdx.x;
    if (e < NE) atomicAdd(&deg[dst[e]], 1);
}

__global__ void __launch_bounds__(256) kScan1(const int* __restrict__ deg,
                                              int* __restrict__ pre, int* __restrict__ bsum){
    __shared__ int sh[256];
    int i = blockIdx.x*256 + threadIdx.x;
    int v = (i < NN) ? deg[i] : 0;
    sh[threadIdx.x] = v;
    __syncthreads();
    for (int o = 1; o < 256; o <<= 1) {
        int t = (threadIdx.x >= o) ? sh[threadIdx.x - o] : 0;
        __syncthreads();
        sh[threadIdx.x] += t;
        __syncthreads();
    }
    if (i < NN) pre[i] = sh[threadIdx.x] - v;   // exclusive
    if (threadIdx.x == 255) bsum[blockIdx.x] = sh[255];
}

__global__ void __launch_bounds__(512) kScan2(int* __restrict__ bsum){
    __shared__ int sh[512];
    int v = (threadIdx.x < NB_SCAN) ? bsum[threadIdx.x] : 0;
    sh[threadIdx.x] = v;
    __syncthreads();
    for (int o = 1; o < 512; o <<= 1) {
        int t = (threadIdx.x >= o) ? sh[threadIdx.x - o] : 0;
        __syncthreads();
        sh[threadIdx.x] += t;
        __syncthreads();
    }
    if (threadIdx.x < NB_SCAN) bsum[threadIdx.x] = sh[threadIdx.x] - v;  // exclusive
}

__global__ void __launch_bounds__(256) kScanFin(int* __restrict__ pre, const int* __restrict__ bsum,
                                                int* __restrict__ cur){
    int i = blockIdx.x*256 + threadIdx.x;
    if (i >= NN) return;
    int v = pre[i] + bsum[blockIdx.x];
    pre[i] = v;
    cur[i] = v;
}

__global__ void __launch_bounds__(256) kScatter(const int* __restrict__ src, const int* __restrict__ dst,
                                                const float* __restrict__ ef,
                                                int* __restrict__ cur, int2* __restrict__ pack){
    int e = blockIdx.x*256 + threadIdx.x;
    if (e >= NE) return;
    int pos = atomicAdd(&cur[dst[e]], 1);
    pack[pos] = make_int2(src[e], __float_as_int(ef[e]));
}
// after kScatter: cur[n] == row-end of node n

// ---------------- per-layer coefficient precompute ----------------
// q_h = Wfc_h @ al_h, r_h = Wfc_h @ ar_h (din vectors, zero-padded to DINP),
// ce_h = We_h . ae_h
template<int DIN, int DINP, int D>
__global__ void kCoef(const float* __restrict__ Wfc, const float* __restrict__ al,
                      const float* __restrict__ ar, const float* __restrict__ We,
                      const float* __restrict__ ae,
                      float* __restrict__ q, float* __restrict__ r, float* __restrict__ ce){
    int t = threadIdx.x;
    if (t < 3*DINP){
        int hd = t / DINP, k = t - hd*DINP;
        float qa = 0.f, ra = 0.f;
        if (k < DIN){
            for (int d = 0; d < D; ++d){
                float w = Wfc[k*3*D + hd*D + d];
                qa += w*al[hd*D+d];
                ra += w*ar[hd*D+d];
            }
        }
        q[t] = qa; r[t] = ra;
    }
    if (t < 3){
        float c = 0.f;
        for (int d = 0; d < D; ++d) c += We[t*D+d]*ae[t*D+d];
        ce[t] = c;
    }
}

// ---------------- layer-1 input prep: h16 (padded fp16) + er3 ----------------
__global__ void __launch_bounds__(256) kPrep1(const float* __restrict__ nf,
    const float* __restrict__ r1, u16* __restrict__ h16, float* __restrict__ er3){
    int n = blockIdx.x*256 + threadIdx.x;
    if (n >= NN) return;
    float h[6];
    #pragma unroll
    for (int k = 0; k < 6; ++k) h[k] = nf[(size_t)n*6 + k];
    __half2 p0 = __floats2half2_rn(h[0], h[1]);
    __half2 p1 = __floats2half2_rn(h[2], h[3]);
    __half2 p2 = __floats2half2_rn(h[4], h[5]);
    __half2 p3 = __floats2half2_rn(0.f, 0.f);
    uint4 raw;
    raw.x = *(u32*)&p0; raw.y = *(u32*)&p1; raw.z = *(u32*)&p2; raw.w = *(u32*)&p3;
    *(uint4*)(h16 + (size_t)n*8) = raw;
    #pragma unroll
    for (int hd = 0; hd < 3; ++hd){
        float er = 0.f;
        #pragma unroll
        for (int k = 0; k < 6; ++k) er += r1[hd*8+k]*h[k];
        er3[n*3+hd] = er;
    }
}

// ---------------- fused layer kernel ----------------
// Phase 1 (edge-par): gather h16[src], logits via q.h, ex=exp(lrelu(.)), cache
//   h+ex in LDS, group-reduce sums.
// Phase 2 (comp-par): agg[h][k] = sum_p ex_p[h]*hsrc_p[k] from LDS.
// Phase 3 (out-par):  o = Wfc^T agg * inv + hres@Wres + b; then either emit
//   fp16 h3 (LAST) or head-mean -> {hmean f32, h16 next, er3 next}.
template<int DINP, int DINR, int D, int LANES, int GP, bool LAST>
__global__ void __launch_bounds__(256) kFused(
    const int* __restrict__ row, const int* __restrict__ rend,
    const int2* __restrict__ pack,
    const float* __restrict__ er3, const float* __restrict__ qc,
    const float* __restrict__ cep, const u16* __restrict__ h16g,
    const float* __restrict__ hres, const float* __restrict__ Wfc,
    const float* __restrict__ Wres, const float* __restrict__ bias,
    float* __restrict__ hmean_o, u16* __restrict__ h16_o,
    float* __restrict__ er3_o, const float* __restrict__ rnext,
    u16* __restrict__ h3_o)
{
    constexpr int W = 3*D, T = W/4, UPE = DINP/2;  // UPE = u32s per edge h row
    __shared__ u32   hs [GP*CAP*UPE];
    __shared__ float exs[GP*CAP*3];
    __shared__ float agg[GP*3*DINP];
    __shared__ float outs[LAST ? 1 : GP*W];
    __shared__ float hms [LAST ? 1 : GP*D];

    const int sub  = threadIdx.x / LANES;
    const int lane = threadIdx.x % LANES;
    const int n = blockIdx.x*GP + sub;
    const bool alive = (n < NN);
    int rs = 0, dg = 0;
    if (alive){ rs = row[n]; dg = rend[n] - rs; }
    float e0 = 0.f, e1 = 0.f, e2 = 0.f;
    if (alive){ e0 = er3[n*3+0]; e1 = er3[n*3+1]; e2 = er3[n*3+2]; }
    const float c0 = cep[0], c1 = cep[1], c2 = cep[2];

    float q[3][DINP];
    #pragma unroll
    for (int hd = 0; hd < 3; ++hd)
        #pragma unroll
        for (int k = 0; k < DINP; ++k) q[hd][k] = qc[hd*DINP+k];

    u32*   hsg = hs  + sub*(CAP*UPE);
    float* exg = exs + sub*(CAP*3);
    float* agz = agg + sub*(3*DINP);

    // ---- phase 1 ----
    float s0 = 0.f, s1 = 0.f, s2 = 0.f;
    for (int p0 = lane; p0 < dg; p0 += LANES){
        int2 pk = pack[rs+p0];
        int sv = pk.x;
        float fv = __int_as_float(pk.y);
        const u32* hp = (const u32*)(h16g + (size_t)sv*DINP);
        u32 raw[UPE];
        if constexpr (UPE == 4){
            uint4 r4 = *(const uint4*)hp;
            raw[0]=r4.x; raw[1]=r4.y; raw[2]=r4.z; raw[3]=r4.w;
        } else {
            uint4 a4 = *(const uint4*)hp;
            uint4 b4 = *(const uint4*)(hp+4);
            raw[0]=a4.x; raw[1]=a4.y; raw[2]=a4.z; raw[3]=a4.w;
            raw[4]=b4.x; raw[5]=b4.y; raw[6]=b4.z; raw[7]=b4.w;
        }
        float hv[DINP];
        #pragma unroll
        for (int w = 0; w < UPE; ++w){
            __half2 hh = *(__half2*)&raw[w];
            float2 f2 = __half22float2(hh);
            hv[2*w] = f2.x; hv[2*w+1] = f2.y;
        }
        float l0 = 0.f, l1 = 0.f, l2 = 0.f;
        #pragma unroll
        for (int k = 0; k < DINP; ++k){
            l0 += q[0][k]*hv[k];
            l1 += q[1][k]*hv[k];
            l2 += q[2][k]*hv[k];
        }
        float x0 = expf(lrelu(l0+e0+c0*fv, 0.2f));
        float x1 = expf(lrelu(l1+e1+c1*fv, 0.2f));
        float x2 = expf(lrelu(l2+e2+c2*fv, 0.2f));
        s0 += x0; s1 += x1; s2 += x2;
        if (p0 < CAP){
            exg[p0*3+0]=x0; exg[p0*3+1]=x1; exg[p0*3+2]=x2;
            if constexpr (UPE == 4){
                uint4 r4; r4.x=raw[0]; r4.y=raw[1]; r4.z=raw[2]; r4.w=raw[3];
                *(uint4*)(hsg + p0*4) = r4;
            } else {
                uint4 a4; a4.x=raw[0]; a4.y=raw[1]; a4.z=raw[2]; a4.w=raw[3];
                uint4 b4; b4.x=raw[4]; b4.y=raw[5]; b4.z=raw[6]; b4.w=raw[7];
                *(uint4*)(hsg + p0*8)     = a4;
                *(uint4*)(hsg + p0*8 + 4) = b4;
            }
        }
    }
    #pragma unroll
    for (int o = LANES/2; o > 0; o >>= 1){
        s0 += __shfl_xor(s0, o);
        s1 += __shfl_xor(s1, o);
        s2 += __shfl_xor(s2, o);
    }
    __syncthreads();

    // ---- phase 2 ----
    const int dc = dg < CAP ? dg : CAP;
    for (int c = lane; c < 3*DINP; c += LANES){
        int hd = c / DINP, k = c - hd*DINP;
        float acc = 0.f;
        for (int p0 = 0; p0 < dc; ++p0){
            float a = exg[p0*3+hd];
            u32 u = hsg[p0*UPE + (k>>1)];
            __half2 hh = *(__half2*)&u;
            float hvv = (k&1) ? __high2float(hh) : __low2float(hh);
            acc += a*hvv;
        }
        for (int p0 = CAP; p0 < dg; ++p0){   // cold overflow path (deg>64: never)
            int2 pk = pack[rs+p0];
            const u16* hp = h16g + (size_t)pk.x*DINP;
            float fv = __int_as_float(pk.y);
            float l = 0.f;
            for (int kk = 0; kk < DINP; ++kk)
                l += qc[hd*DINP+kk]*__half2float(*(const __half*)(hp+kk));
            float eh = (hd==0)?e0:((hd==1)?e1:e2);
            float a = expf(lrelu(l+eh+cep[hd]*fv, 0.2f));
            acc += a*__half2float(*(const __half*)(hp+k));
        }
        agz[c] = acc;
    }
    __syncthreads();

    // ---- phase 3 ----
    if (alive && lane < T){
        int j = lane;
        int hd = (j*4)/D;
        float sh = (hd==0)?s0:((hd==1)?s1:s2);
        float inv = sh > 0.f ? 1.f/sh : 0.f;
        const float4* Wfc4 = (const float4*)Wfc;
        const float4* Wr4  = (const float4*)Wres;
        float4 a4 = make_float4(0.f,0.f,0.f,0.f);
        float4 r4 = ((const float4*)bias)[j];
        #pragma unroll
        for (int k = 0; k < DINR; ++k){
            float av = agz[hd*DINP+k];
            float4 w = Wfc4[k*T + j];
            a4.x += av*w.x; a4.y += av*w.y; a4.z += av*w.z; a4.w += av*w.w;
            float hk = hres[(size_t)n*DINR + k];
            float4 wr = Wr4[k*T + j];
            r4.x += hk*wr.x; r4.y += hk*wr.y; r4.z += hk*wr.z; r4.w += hk*wr.w;
        }
        float4 o;
        o.x = a4.x*inv + r4.x; o.y = a4.y*inv + r4.y;
        o.z = a4.z*inv + r4.z; o.w = a4.w*inv + r4.w;
        if constexpr (LAST){
            __half2 ha = __floats2half2_rn(o.x, o.y);
            __half2 hb = __floats2half2_rn(o.z, o.w);
            uint2 st; st.x = *(u32*)&ha; st.y = *(u32*)&hb;
            *(uint2*)(h3_o + (size_t)n*W + j*4) = st;
        } else {
            float* og = outs + sub*W;
            og[j*4+0]=o.x; og[j*4+1]=o.y; og[j*4+2]=o.z; og[j*4+3]=o.w;
        }
    }
    if constexpr (!LAST){
        __syncthreads();
        if (alive && lane < D){
            const float* og = outs + sub*W;
            float hm = (og[lane] + og[D+lane] + og[2*D+lane]) * (1.f/3.f);
            hmean_o[(size_t)n*D + lane] = hm;
            __half hh = __float2half(hm);
            h16_o[(size_t)n*D + lane] = *(u16*)&hh;
            hms[sub*D + lane] = hm;
        }
        __syncthreads();
        if (alive && lane < 3){
            float er = 0.f;
            #pragma unroll
            for (int d = 0; d < D; ++d) er += rnext[lane*D+d]*hms[sub*D+d];
            er3_o[n*3+lane] = er;
        }
    }
}

// ---------------- MLP head + global max (fp16 h3 input) ----------------
__global__ void __launch_bounds__(256) kHead(const u16* __restrict__ h3,
    const float* __restrict__ L1a_w, const float* __restrict__ L1a_b,
    const float* __restrict__ L1b_w, const float* __restrict__ L1b_b,
    const float* __restrict__ L1c_w, const float* __restrict__ L1c_b,
    const float* __restrict__ L2_w, const float* __restrict__ L2_b,
    float* __restrict__ out)
{
    __shared__ float red[256];
    int n = blockIdx.x*256 + threadIdx.x;
    float y = -INFINITY;
    if (n < NN) {
        const u16* p = h3 + (size_t)n*96;
        float acc = L2_b[0];
        #pragma unroll
        for (int h = 0; h < 3; ++h) {
            float hb[32];
            #pragma unroll
            for (int d = 0; d < 32; ++d) hb[d] = __half2float(*(const __half*)(p + h*32 + d));
            float x1[16];
            #pragma unroll
            for (int i = 0; i < 16; ++i) {
                float v = L1a_b[i];
                #pragma unroll
                for (int d = 0; d < 32; ++d) v += hb[d]*L1a_w[d*16+i];
                x1[i] = lrelu(v, 0.01f);
            }
            float x2[4];
            #pragma unroll
            for (int i = 0; i < 4; ++i) {
                float v = L1b_b[i];
                #pragma unroll
                for (int d = 0; d < 16; ++d) v += x1[d]*L1b_w[d*4+i];
                x2[i] = lrelu(v, 0.01f);
            }
            float v = L1c_b[0];
            #pragma unroll
            for (int d = 0; d < 4; ++d) v += x2[d]*L1c_w[d];
            acc += v*L2_w[h];
        }
        y = acc;
    }
    red[threadIdx.x] = y;
    __syncthreads();
    for (int o = 128; o > 0; o >>= 1) {
        if (threadIdx.x < o) red[threadIdx.x] = fmaxf(red[threadIdx.x], red[threadIdx.x+o]);
        __syncthreads();
    }
    if (threadIdx.x == 0) atomicMaxF(out, red[0]);
}

extern "C" void kernel_launch(void* const* d_in, const int* in_sizes, int n_in,
                              void* d_out, int out_size, void* d_ws, size_t ws_size,
                              hipStream_t stream) {
    const float* nf  = (const float*)d_in[0];
    const float* ef  = (const float*)d_in[1];
    const float* W1  = (const float*)d_in[2];
    const float* We1 = (const float*)d_in[3];
    const float* al1 = (const float*)d_in[4];
    const float* ar1 = (const float*)d_in[5];
    const float* ae1 = (const float*)d_in[6];
    const float* Wr1 = (const float*)d_in[7];
    const float* b1  = (const float*)d_in[8];
    const float* W2  = (const float*)d_in[9];
    const float* We2 = (const float*)d_in[10];
    const float* al2 = (const float*)d_in[11];
    const float* ar2 = (const float*)d_in[12];
    const float* ae2 = (const float*)d_in[13];
    const float* Wr2 = (const float*)d_in[14];
    const float* b2  = (const float*)d_in[15];
    const float* W3  = (const float*)d_in[16];
    const float* We3 = (const float*)d_in[17];
    const float* al3 = (const float*)d_in[18];
    const float* ar3 = (const float*)d_in[19];
    const float* ae3 = (const float*)d_in[20];
    const float* Wr3 = (const float*)d_in[21];
    const float* b3  = (const float*)d_in[22];
    const float* L1a_w = (const float*)d_in[23];
    const float* L1a_b = (const float*)d_in[24];
    const float* L1b_w = (const float*)d_in[25];
    const float* L1b_b = (const float*)d_in[26];
    const float* L1c_w = (const float*)d_in[27];
    const float* L1c_b = (const float*)d_in[28];
    const float* L2_w  = (const float*)d_in[29];
    const float* L2_b  = (const float*)d_in[30];
    const int* src = (const int*)d_in[31];
    const int* dst = (const int*)d_in[32];
    float* out = (float*)d_out;

    // ---- workspace layout ----
    float* ws = (float*)d_ws;
    u16* h16_1 = (u16*)ws;                      // [N,8]  fp16
    u16* h16_2 = h16_1 + (size_t)NN*8;          // [N,8]  fp16
    u16* h16_3 = h16_2 + (size_t)NN*8;          // [N,16] fp16
    float* f   = ws + (size_t)NN*16;            // (32 u16 = 16 floats)
    float* hm2  = f;  f += (size_t)NN*8;        // layer-2 input mean, f32
    float* hm3  = f;  f += (size_t)NN*16;       // layer-3 input mean, f32
    float* er3a = f;  f += (size_t)NN*3;
    float* er3b = f;  f += (size_t)NN*3;
    u16* h3g   = (u16*)f; f += (size_t)NN*48;   // [N,96] fp16
    float* coef = f;  f += 256;
    // coef: q1@0 r1@24 q2@48 r2@72 q3@96 r3@144 ce1@192 ce2@195 ce3@198
    int* deg  = (int*)f;
    int* rowv = deg + NN;
    int* curv = rowv + NN;
    int* bsum = curv + NN;
    int2* pack = (int2*)(bsum + 512);           // [E] {src, ef-bits}

    const int gN = (NN + 255)/256;
    const int gE = (NE + 255)/256;

    kInitOut<<<1,1,0,stream>>>(out);

    // ---- CSR build (by dst) ----
    hipMemsetAsync(deg, 0, NN*sizeof(int), stream);
    kHist<<<gE,256,0,stream>>>(dst, deg);
    kScan1<<<NB_SCAN,256,0,stream>>>(deg, rowv, bsum);
    kScan2<<<1,512,0,stream>>>(bsum);
    kScanFin<<<NB_SCAN,256,0,stream>>>(rowv, bsum, curv);
    kScatter<<<gE,256,0,stream>>>(src, dst, ef, curv, pack);

    // ---- coefficients ----
    kCoef<6,8,8>  <<<1,128,0,stream>>>(W1, al1, ar1, We1, ae1, coef+0,  coef+24,  coef+192);
    kCoef<8,8,16> <<<1,128,0,stream>>>(W2, al2, ar2, We2, ae2, coef+48, coef+72,  coef+195);
    kCoef<16,16,32><<<1,128,0,stream>>>(W3, al3, ar3, We3, ae3, coef+96, coef+144, coef+198);

    // ---- layer-1 input prep ----
    kPrep1<<<gN,256,0,stream>>>(nf, coef+24, h16_1, er3a);

    // ---- Layer 1: DINP=8(pad6), DINR=6, D=8, LANES=16, GP=16 ----
    kFused<8,6,8,16,16,false><<<(NN+15)/16,256,0,stream>>>(rowv, curv, pack,
        er3a, coef+0, coef+192, h16_1, nf, W1, Wr1, b1,
        hm2, h16_2, er3b, coef+72, nullptr);

    // ---- Layer 2: DINP=8, DINR=8, D=16, LANES=16, GP=16 ----
    kFused<8,8,16,16,16,false><<<(NN+15)/16,256,0,stream>>>(rowv, curv, pack,
        er3b, coef+48, coef+195, h16_2, hm2, W2, Wr2, b2,
        hm3, h16_3, er3a, coef+144, nullptr);

    // ---- Layer 3: DINP=16, DINR=16, D=32, LANES=32, GP=8 ----
    kFused<16,16,32,32,8,true><<<(NN+7)/8,256,0,stream>>>(rowv, curv, pack,
        er3a, coef+96, coef+198, h16_3, hm3, W3, Wr3, b3,
        nullptr, nullptr, nullptr, nullptr, h3g);

    // ---- MLP head + global max ----
    kHead<<<gN,256,0,stream>>>(h3g, L1a_w, L1a_b, L1b_w, L1b_b, L1c_w, L1c_b, L2_w, L2_b, out);
}

// Round 5
// 338.312 us; speedup vs baseline: 3.6209x; 1.0209x over previous
//
#include <hip/hip_runtime.h>
#include <hip/hip_fp16.h>
#include <math.h>

#define NN 100000
#define NE 1000000
#define NB_SCAN ((NN + 255) / 256)   // 391
#define NPB 32                        // nodes per block (NN % NPB == 0 -> 3125 blocks)
#define ECAP 576                      // cached edges per block (mean 320, sd ~18; P(>576) < 1e-30)

typedef unsigned int   u32;
typedef unsigned short u16;

__device__ __forceinline__ float lrelu(float x, float sl){ return x >= 0.f ? x : sl*x; }

__device__ __forceinline__ void atomicMaxF(float* a, float v){
    if (v >= 0.f) atomicMax((int*)a, __float_as_int(v));
    else          atomicMin((unsigned int*)a, __float_as_uint(v));
}

__global__ void kInitOut(float* out){ out[0] = -INFINITY; }

// ---------------- CSR build ----------------
__global__ void __launch_bounds__(256) kHist(const int* __restrict__ dst, int* __restrict__ deg){
    int e = blockIdx.x*256 + threadIdx.x;
    if (e < NE) atomicAdd(&deg[dst[e]], 1);
}

__global__ void __launch_bounds__(256) kScan1(const int* __restrict__ deg,
                                              int* __restrict__ pre, int* __restrict__ bsum){
    __shared__ int sh[256];
    int i = blockIdx.x*256 + threadIdx.x;
    int v = (i < NN) ? deg[i] : 0;
    sh[threadIdx.x] = v;
    __syncthreads();
    for (int o = 1; o < 256; o <<= 1) {
        int t = (threadIdx.x >= o) ? sh[threadIdx.x - o] : 0;
        __syncthreads();
        sh[threadIdx.x] += t;
        __syncthreads();
    }
    if (i < NN) pre[i] = sh[threadIdx.x] - v;   // exclusive
    if (threadIdx.x == 255) bsum[blockIdx.x] = sh[255];
}

__global__ void __launch_bounds__(512) kScan2(int* __restrict__ bsum){
    __shared__ int sh[512];
    int v = (threadIdx.x < NB_SCAN) ? bsum[threadIdx.x] : 0;
    sh[threadIdx.x] = v;
    __syncthreads();
    for (int o = 1; o < 512; o <<= 1) {
        int t = (threadIdx.x >= o) ? sh[threadIdx.x - o] : 0;
        __syncthreads();
        sh[threadIdx.x] += t;
        __syncthreads();
    }
    if (threadIdx.x < NB_SCAN) bsum[threadIdx.x] = sh[threadIdx.x] - v;  // exclusive
}

__global__ void __launch_bounds__(256) kScanFin(int* __restrict__ pre, const int* __restrict__ bsum,
                                                int* __restrict__ cur){
    int i = blockIdx.x*256 + threadIdx.x;
    if (i >= NN) return;
    int v = pre[i] + bsum[blockIdx.x];
    pre[i] = v;
    cur[i] = v;
}

__global__ void __launch_bounds__(256) kScatter(const int* __restrict__ src, const int* __restrict__ dst,
                                                const float* __restrict__ ef,
                                                int* __restrict__ cur, int2* __restrict__ pack){
    int e = blockIdx.x*256 + threadIdx.x;
    if (e >= NE) return;
    int pos = atomicAdd(&cur[dst[e]], 1);
    pack[pos] = make_int2(src[e], __float_as_int(ef[e]));
}
// after CSR build: rowv[n] = row start; rowv[n+1] = row end (contiguous)

// ---------------- per-layer coefficient precompute ----------------
// q_h = Wfc_h @ al_h, r_h = Wfc_h @ ar_h (din vectors, zero-padded to DINP),
// ce_h = We_h . ae_h
template<int DIN, int DINP, int D>
__global__ void kCoef(const float* __restrict__ Wfc, const float* __restrict__ al,
                      const float* __restrict__ ar, const float* __restrict__ We,
                      const float* __restrict__ ae,
                      float* __restrict__ q, float* __restrict__ r, float* __restrict__ ce){
    int t = threadIdx.x;
    if (t < 3*DINP){
        int hd = t / DINP, k = t - hd*DINP;
        float qa = 0.f, ra = 0.f;
        if (k < DIN){
            for (int d = 0; d < D; ++d){
                float w = Wfc[k*3*D + hd*D + d];
                qa += w*al[hd*D+d];
                ra += w*ar[hd*D+d];
            }
        }
        q[t] = qa; r[t] = ra;
    }
    if (t < 3){
        float c = 0.f;
        for (int d = 0; d < D; ++d) c += We[t*D+d]*ae[t*D+d];
        ce[t] = c;
    }
}

// ---------------- layer-1 node-table prep ----------------
// ntab1 row (8 u32): [0..3]=8 halves (6 real + 2 zero), [4..6]=el0..2 f32, [7]=pad
__global__ void __launch_bounds__(256) kPrep1(const float* __restrict__ nf,
    const float* __restrict__ q1, const float* __restrict__ r1,
    u32* __restrict__ ntab1, float* __restrict__ er3a){
    int n = blockIdx.x*256 + threadIdx.x;
    if (n >= NN) return;
    float h[6];
    #pragma unroll
    for (int k = 0; k < 6; ++k) h[k] = nf[(size_t)n*6 + k];
    u32 row[8];
    __half2 p0 = __floats2half2_rn(h[0], h[1]);
    __half2 p1 = __floats2half2_rn(h[2], h[3]);
    __half2 p2 = __floats2half2_rn(h[4], h[5]);
    __half2 p3 = __floats2half2_rn(0.f, 0.f);
    row[0] = *(u32*)&p0; row[1] = *(u32*)&p1; row[2] = *(u32*)&p2; row[3] = *(u32*)&p3;
    #pragma unroll
    for (int hd = 0; hd < 3; ++hd){
        float el = 0.f, er = 0.f;
        #pragma unroll
        for (int k = 0; k < 6; ++k){ el += q1[hd*8+k]*h[k]; er += r1[hd*8+k]*h[k]; }
        row[4+hd] = __float_as_uint(el);
        er3a[(size_t)n*3+hd] = er;
    }
    row[7] = 0;
    uint4* rp = (uint4*)(ntab1 + (size_t)n*8);
    rp[0] = make_uint4(row[0],row[1],row[2],row[3]);
    rp[1] = make_uint4(row[4],row[5],row[6],row[7]);
}

// ---------------- block-cooperative fused layer ----------------
// Block owns NPB consecutive nodes; their CSR edges are one contiguous range.
// Phase 1 (edge-par, all 256 threads): gather node row (h fp16 + el f32),
//   ex = exp(lrelu(el + er + ce*ef)), cache ex+h in LDS.
// Phase 2 (slot-par): s[nd][h] and agg[nd][h][k] from LDS (deterministic).
// Phase 3 (slot-par): o = Wfc^T agg * inv + hres@Wres + b; emit fp16 h3 (LAST)
//   or next-layer {hmean f32, packed node row, er3}.
template<int DINP, int DINR, int D, bool LAST>
__global__ void __launch_bounds__(256) kFused(
    const int* __restrict__ rowv, const int2* __restrict__ pack,
    const u32* __restrict__ ntab, const float* __restrict__ er3,
    const float* __restrict__ cep, const float* __restrict__ hres,
    const float* __restrict__ Wfc, const float* __restrict__ Wres,
    const float* __restrict__ bias,
    float* __restrict__ hmean_o, u32* __restrict__ ntab_next,
    float* __restrict__ er3_next, const float* __restrict__ qnext,
    const float* __restrict__ rnext, u16* __restrict__ h3_o)
{
    constexpr int W = 3*D, T = W/4, CH = 3*DINP, UPE = DINP/2, LST = UPE+1;
    constexpr int ROWU = (UPE+4) & ~1;    // u32 per node row (8 or 12)
    __shared__ int   rowoff[NPB+1];
    __shared__ unsigned char nid[ECAP];
    __shared__ float exl[ECAP*3];
    __shared__ u32   hsl[ECAP*LST];
    __shared__ float s3[NPB*3];
    __shared__ float erl[NPB*3];
    __shared__ float agg[NPB*CH];
    __shared__ float outs[LAST ? 1 : NPB*W];
    __shared__ float hml [LAST ? 1 : NPB*D];

    const int tid = threadIdx.x;
    const int n0  = blockIdx.x*NPB;

    // ---- phase 0: block setup ----
    if (tid <= NPB) rowoff[tid] = (n0+tid < NN) ? rowv[n0+tid] : NE;
    for (int i = tid; i < NPB*3; i += 256){ s3[i] = 0.f; erl[i] = er3[(size_t)n0*3 + i]; }
    for (int i = tid; i < NPB*CH; i += 256) agg[i] = 0.f;
    __syncthreads();
    const int eb  = rowoff[0];
    const int ted = rowoff[NPB] - eb;
    if (tid < NPB){
        int lo = rowoff[tid]-eb, hi = rowoff[tid+1]-eb;
        if (hi > ECAP) hi = ECAP;
        for (int p = lo; p < hi; ++p) nid[p] = (unsigned char)tid;
    }
    __syncthreads();

    const float c0 = cep[0], c1 = cep[1], c2 = cep[2];

    // ---- phase 1: edge-parallel gather + softmax numerator ----
    for (int e = tid; e < ted; e += 256){
        int2 pk = pack[eb+e];
        const int   sv = pk.x;
        const float fv = __int_as_float(pk.y);
        const uint4* rp = (const uint4*)(ntab + (size_t)sv*ROWU);
        uint4 A = rp[0];
        uint4 B = rp[1];
        float el0, el1, el2;
        uint4 Cw;
        if constexpr (UPE == 4){
            el0 = __uint_as_float(B.x); el1 = __uint_as_float(B.y); el2 = __uint_as_float(B.z);
        } else {
            Cw = rp[2];
            el0 = __uint_as_float(Cw.x); el1 = __uint_as_float(Cw.y); el2 = __uint_as_float(Cw.z);
        }
        int nd;
        if (e < ECAP) nd = nid[e];
        else { int lo=0, hi=NPB, ea=eb+e;
               while (hi-lo > 1){ int mid=(lo+hi)>>1; if (rowoff[mid] <= ea) lo=mid; else hi=mid; }
               nd = lo; }
        float x0 = expf(lrelu(el0 + erl[nd*3+0] + c0*fv, 0.2f));
        float x1 = expf(lrelu(el1 + erl[nd*3+1] + c1*fv, 0.2f));
        float x2 = expf(lrelu(el2 + erl[nd*3+2] + c2*fv, 0.2f));
        if (e < ECAP){
            exl[e*3+0] = x0; exl[e*3+1] = x1; exl[e*3+2] = x2;
            hsl[e*LST+0] = A.x; hsl[e*LST+1] = A.y; hsl[e*LST+2] = A.z; hsl[e*LST+3] = A.w;
            if constexpr (UPE == 8){
                hsl[e*LST+4] = B.x; hsl[e*LST+5] = B.y; hsl[e*LST+6] = B.z; hsl[e*LST+7] = B.w;
            }
        } else {   // overflow fallback (statistically never taken)
            atomicAdd(&s3[nd*3+0], x0); atomicAdd(&s3[nd*3+1], x1); atomicAdd(&s3[nd*3+2], x2);
            u32 wds[UPE];
            wds[0]=A.x; wds[1]=A.y; wds[2]=A.z; wds[3]=A.w;
            if constexpr (UPE == 8){ wds[4]=B.x; wds[5]=B.y; wds[6]=B.z; wds[7]=B.w; }
            #pragma unroll
            for (int w = 0; w < UPE; ++w){
                float2 f2 = __half22float2(*(__half2*)&wds[w]);
                atomicAdd(&agg[nd*CH + 0*DINP + 2*w  ], x0*f2.x);
                atomicAdd(&agg[nd*CH + 0*DINP + 2*w+1], x0*f2.y);
                atomicAdd(&agg[nd*CH + 1*DINP + 2*w  ], x1*f2.x);
                atomicAdd(&agg[nd*CH + 1*DINP + 2*w+1], x1*f2.y);
                atomicAdd(&agg[nd*CH + 2*DINP + 2*w  ], x2*f2.x);
                atomicAdd(&agg[nd*CH + 2*DINP + 2*w+1], x2*f2.y);
            }
        }
    }
    __syncthreads();

    // ---- phase 2a: softmax denominators (deterministic) ----
    for (int slot = tid; slot < NPB*3; slot += 256){
        int nd = slot/3, hd = slot - nd*3;
        int lo = rowoff[nd]-eb, hi = rowoff[nd+1]-eb; if (hi > ECAP) hi = ECAP;
        float acc = 0.f;
        for (int p = lo; p < hi; ++p) acc += exl[p*3+hd];
        s3[slot] += acc;
    }
    // ---- phase 2b: per-(node,head,channel) aggregation ----
    for (int slot = tid; slot < NPB*CH; slot += 256){
        int nd = slot/CH, c = slot - nd*CH, hd = c/DINP, k = c - hd*DINP;
        int lo = rowoff[nd]-eb, hi = rowoff[nd+1]-eb; if (hi > ECAP) hi = ECAP;
        float acc = 0.f;
        for (int p = lo; p < hi; ++p){
            float a = exl[p*3+hd];
            __half2 hh = *(__half2*)&hsl[p*LST + (k>>1)];
            float hv = (k&1) ? __high2float(hh) : __low2float(hh);
            acc += a*hv;
        }
        agg[slot] += acc;
    }
    __syncthreads();

    // ---- phase 3: output projection + finalize ----
    for (int slot = tid; slot < NPB*T; slot += 256){
        int nd = slot/T, j = slot - nd*T;
        int n  = n0 + nd;
        int hd = (j*4)/D;
        float sv = s3[nd*3+hd];
        float inv = sv > 0.f ? 1.f/sv : 0.f;
        const float4* Wf4 = (const float4*)Wfc;
        const float4* Wr4 = (const float4*)Wres;
        float4 a4 = make_float4(0.f,0.f,0.f,0.f);
        float4 r4 = ((const float4*)bias)[j];
        #pragma unroll
        for (int k = 0; k < DINR; ++k){
            float av = agg[nd*CH + hd*DINP + k];
            float4 w = Wf4[k*T + j];
            a4.x += av*w.x; a4.y += av*w.y; a4.z += av*w.z; a4.w += av*w.w;
            float hk = hres[(size_t)n*DINR + k];
            float4 wr = Wr4[k*T + j];
            r4.x += hk*wr.x; r4.y += hk*wr.y; r4.z += hk*wr.z; r4.w += hk*wr.w;
        }
        float4 o;
        o.x = a4.x*inv + r4.x; o.y = a4.y*inv + r4.y;
        o.z = a4.z*inv + r4.z; o.w = a4.w*inv + r4.w;
        if constexpr (LAST){
            __half2 ha = __floats2half2_rn(o.x, o.y);
            __half2 hb = __floats2half2_rn(o.z, o.w);
            uint2 st; st.x = *(u32*)&ha; st.y = *(u32*)&hb;
            *(uint2*)(h3_o + (size_t)n*W + j*4) = st;
        } else {
            outs[nd*W + j*4+0] = o.x; outs[nd*W + j*4+1] = o.y;
            outs[nd*W + j*4+2] = o.z; outs[nd*W + j*4+3] = o.w;
        }
    }

    // ---- emission of next-layer inputs ----
    if constexpr (!LAST){
        constexpr int ROWUn = (D/2 + 4) & ~1;
        __syncthreads();
        for (int slot = tid; slot < NPB*D; slot += 256){
            int nd = slot/D, d = slot - nd*D;
            float hm = (outs[nd*W + d] + outs[nd*W + D + d] + outs[nd*W + 2*D + d]) * (1.f/3.f);
            hml[nd*D + d] = hm;
            hmean_o[(size_t)(n0+nd)*D + d] = hm;
        }
        __syncthreads();
        for (int slot = tid; slot < NPB*(D/2); slot += 256){
            int nd = slot/(D/2), w = slot - nd*(D/2);
            __half2 hh = __floats2half2_rn(hml[nd*D + 2*w], hml[nd*D + 2*w + 1]);
            ntab_next[(size_t)(n0+nd)*ROWUn + w] = *(u32*)&hh;
        }
        for (int slot = tid; slot < NPB*6; slot += 256){
            int nd = slot/6, c = slot - nd*6;
            int hd = (c < 3) ? c : (c - 3);
            const float* cf = (c < 3) ? qnext : rnext;
            float acc = 0.f;
            #pragma unroll
            for (int d = 0; d < D; ++d) acc += cf[hd*D + d]*hml[nd*D + d];
            if (c < 3) ntab_next[(size_t)(n0+nd)*ROWUn + D/2 + hd] = __float_as_uint(acc);
            else       er3_next[(size_t)(n0+nd)*3 + hd] = acc;
        }
    }
}

// ---------------- MLP head + global max (fp16 h3 input) ----------------
__global__ void __launch_bounds__(256) kHead(const u16* __restrict__ h3,
    const float* __restrict__ L1a_w, const float* __restrict__ L1a_b,
    const float* __restrict__ L1b_w, const float* __restrict__ L1b_b,
    const float* __restrict__ L1c_w, const float* __restrict__ L1c_b,
    const float* __restrict__ L2_w, const float* __restrict__ L2_b,
    float* __restrict__ out)
{
    __shared__ float red[256];
    int n = blockIdx.x*256 + threadIdx.x;
    float y = -INFINITY;
    if (n < NN) {
        const u16* p = h3 + (size_t)n*96;
        float acc = L2_b[0];
        #pragma unroll
        for (int h = 0; h < 3; ++h) {
            float hb[32];
            #pragma unroll
            for (int d = 0; d < 32; ++d) hb[d] = __half2float(*(const __half*)(p + h*32 + d));
            float x1[16];
            #pragma unroll
            for (int i = 0; i < 16; ++i) {
                float v = L1a_b[i];
                #pragma unroll
                for (int d = 0; d < 32; ++d) v += hb[d]*L1a_w[d*16+i];
                x1[i] = lrelu(v, 0.01f);
            }
            float x2[4];
            #pragma unroll
            for (int i = 0; i < 4; ++i) {
                float v = L1b_b[i];
                #pragma unroll
                for (int d = 0; d < 16; ++d) v += x1[d]*L1b_w[d*4+i];
                x2[i] = lrelu(v, 0.01f);
            }
            float v = L1c_b[0];
            #pragma unroll
            for (int d = 0; d < 4; ++d) v += x2[d]*L1c_w[d];
            acc += v*L2_w[h];
        }
        y = acc;
    }
    red[threadIdx.x] = y;
    __syncthreads();
    for (int o = 128; o > 0; o >>= 1) {
        if (threadIdx.x < o) red[threadIdx.x] = fmaxf(red[threadIdx.x], red[threadIdx.x+o]);
        __syncthreads();
    }
    if (threadIdx.x == 0) atomicMaxF(out, red[0]);
}

extern "C" void kernel_launch(void* const* d_in, const int* in_sizes, int n_in,
                              void* d_out, int out_size, void* d_ws, size_t ws_size,
                              hipStream_t stream) {
    const float* nf  = (const float*)d_in[0];
    const float* ef  = (const float*)d_in[1];
    const float* W1  = (const float*)d_in[2];
    const float* We1 = (const float*)d_in[3];
    const float* al1 = (const float*)d_in[4];
    const float* ar1 = (const float*)d_in[5];
    const float* ae1 = (const float*)d_in[6];
    const float* Wr1 = (const float*)d_in[7];
    const float* b1  = (const float*)d_in[8];
    const float* W2  = (const float*)d_in[9];
    const float* We2 = (const float*)d_in[10];
    const float* al2 = (const float*)d_in[11];
    const float* ar2 = (const float*)d_in[12];
    const float* ae2 = (const float*)d_in[13];
    const float* Wr2 = (const float*)d_in[14];
    const float* b2  = (const float*)d_in[15];
    const float* W3  = (const float*)d_in[16];
    const float* We3 = (const float*)d_in[17];
    const float* al3 = (const float*)d_in[18];
    const float* ar3 = (const float*)d_in[19];
    const float* ae3 = (const float*)d_in[20];
    const float* Wr3 = (const float*)d_in[21];
    const float* b3  = (const float*)d_in[22];
    const float* L1a_w = (const float*)d_in[23];
    const float* L1a_b = (const float*)d_in[24];
    const float* L1b_w = (const float*)d_in[25];
    const float* L1b_b = (const float*)d_in[26];
    const float* L1c_w = (const float*)d_in[27];
    const float* L1c_b = (const float*)d_in[28];
    const float* L2_w  = (const float*)d_in[29];
    const float* L2_b  = (const float*)d_in[30];
    const int* src = (const int*)d_in[31];
    const int* dst = (const int*)d_in[32];
    float* out = (float*)d_out;

    // ---- workspace layout ----
    float* ws = (float*)d_ws;
    u32* ntab1 = (u32*)ws;                        // [N,8]  u32
    u32* ntab2 = ntab1 + (size_t)NN*8;            // [N,8]  u32
    u32* ntab3 = ntab2 + (size_t)NN*8;            // [N,12] u32
    float* f   = (float*)(ntab3 + (size_t)NN*12);
    float* hm2  = f;  f += (size_t)NN*8;          // layer-2 residual input (f32)
    float* hm3  = f;  f += (size_t)NN*16;         // layer-3 residual input (f32)
    float* er3a = f;  f += (size_t)NN*3;
    float* er3b = f;  f += (size_t)NN*3;
    u16* h3g   = (u16*)f; f += (size_t)NN*48;     // [N,96] fp16
    float* coef = f;  f += 256;
    // coef: q1@0 r1@24 q2@48 r2@72 q3@96 r3@144 ce1@192 ce2@196 ce3@200
    int* deg  = (int*)f;
    int* rowv = deg + NN;
    int* curv = rowv + NN;
    int* bsum = curv + NN;
    int2* pack = (int2*)(bsum + 512);             // [E] {src, ef-bits}

    const int gN = (NN + 255)/256;
    const int gE = (NE + 255)/256;
    const int gF = NN/NPB;                        // 3125

    kInitOut<<<1,1,0,stream>>>(out);

    // ---- CSR build (by dst) ----
    hipMemsetAsync(deg, 0, NN*sizeof(int), stream);
    kHist<<<gE,256,0,stream>>>(dst, deg);
    kScan1<<<NB_SCAN,256,0,stream>>>(deg, rowv, bsum);
    kScan2<<<1,512,0,stream>>>(bsum);
    kScanFin<<<NB_SCAN,256,0,stream>>>(rowv, bsum, curv);
    kScatter<<<gE,256,0,stream>>>(src, dst, ef, curv, pack);

    // ---- coefficients ----
    kCoef<6,8,8>   <<<1,64,0,stream>>>(W1, al1, ar1, We1, ae1, coef+0,  coef+24,  coef+192);
    kCoef<8,8,16>  <<<1,64,0,stream>>>(W2, al2, ar2, We2, ae2, coef+48, coef+72,  coef+196);
    kCoef<16,16,32><<<1,64,0,stream>>>(W3, al3, ar3, We3, ae3, coef+96, coef+144, coef+200);

    // ---- layer-1 node table ----
    kPrep1<<<gN,256,0,stream>>>(nf, coef+0, coef+24, ntab1, er3a);

    // ---- Layer 1: DINP=8(pad 6), DINR=6, D=8 ----
    kFused<8,6,8,false><<<gF,256,0,stream>>>(rowv, pack, ntab1, er3a, coef+192, nf,
        W1, Wr1, b1, hm2, ntab2, er3b, coef+48, coef+72, nullptr);

    // ---- Layer 2: DINP=8, DINR=8, D=16 ----
    kFused<8,8,16,false><<<gF,256,0,stream>>>(rowv, pack, ntab2, er3b, coef+196, hm2,
        W2, Wr2, b2, hm3, ntab3, er3a, coef+96, coef+144, nullptr);

    // ---- Layer 3: DINP=16, DINR=16, D=32 ----
    kFused<16,16,32,true><<<gF,256,0,stream>>>(rowv, pack, ntab3, er3a, coef+200, hm3,
        W3, Wr3, b3, nullptr, nullptr, nullptr, nullptr, nullptr, h3g);

    // ---- MLP head + global max ----
    kHead<<<gN,256,0,stream>>>(h3g, L1a_w, L1a_b, L1b_w, L1b_b, L1c_w, L1c_b, L2_w, L2_b, out);
}

// Round 6
// 308.167 us; speedup vs baseline: 3.9751x; 1.0978x over previous
//
#include <hip/hip_runtime.h>
#include <hip/hip_fp16.h>
#include <math.h>

#define NN 100000
#define NE 1000000
#define NB_SCAN ((NN + 255) / 256)   // 391

typedef unsigned int   u32;
typedef unsigned short u16;

__device__ __forceinline__ float lrelu(float x, float sl){ return x >= 0.f ? x : sl*x; }

__device__ __forceinline__ void atomicMaxF(float* a, float v){
    if (v >= 0.f) atomicMax((int*)a, __float_as_int(v));
    else          atomicMin((unsigned int*)a, __float_as_uint(v));
}

__global__ void kInitOut(float* out){ out[0] = -INFINITY; }

// ---------------- CSR build ----------------
__global__ void __launch_bounds__(256) kHist(const int* __restrict__ dst, int* __restrict__ deg){
    int e = blockIdx.x*256 + threadIdx.x;
    if (e < NE) atomicAdd(&deg[dst[e]], 1);
}

__global__ void __launch_bounds__(256) kScan1(const int* __restrict__ deg,
                                              int* __restrict__ pre, int* __restrict__ bsum){
    __shared__ int sh[256];
    int i = blockIdx.x*256 + threadIdx.x;
    int v = (i < NN) ? deg[i] : 0;
    sh[threadIdx.x] = v;
    __syncthreads();
    for (int o = 1; o < 256; o <<= 1) {
        int t = (threadIdx.x >= o) ? sh[threadIdx.x - o] : 0;
        __syncthreads();
        sh[threadIdx.x] += t;
        __syncthreads();
    }
    if (i < NN) pre[i] = sh[threadIdx.x] - v;   // exclusive
    if (threadIdx.x == 255) bsum[blockIdx.x] = sh[255];
}

__global__ void __launch_bounds__(512) kScan2(int* __restrict__ bsum){
    __shared__ int sh[512];
    int v = (threadIdx.x < NB_SCAN) ? bsum[threadIdx.x] : 0;
    sh[threadIdx.x] = v;
    __syncthreads();
    for (int o = 1; o < 512; o <<= 1) {
        int t = (threadIdx.x >= o) ? sh[threadIdx.x - o] : 0;
        __syncthreads();
        sh[threadIdx.x] += t;
        __syncthreads();
    }
    if (threadIdx.x < NB_SCAN) bsum[threadIdx.x] = sh[threadIdx.x] - v;  // exclusive
}

__global__ void __launch_bounds__(256) kScanFin(int* __restrict__ pre, const int* __restrict__ bsum,
                                                int* __restrict__ cur){
    int i = blockIdx.x*256 + threadIdx.x;
    if (i >= NN) return;
    int v = pre[i] + bsum[blockIdx.x];
    pre[i] = v;
    cur[i] = v;
}

__global__ void __launch_bounds__(256) kScatter(const int* __restrict__ src, const int* __restrict__ dst,
                                                const float* __restrict__ ef,
                                                int* __restrict__ cur, int2* __restrict__ pack){
    int e = blockIdx.x*256 + threadIdx.x;
    if (e >= NE) return;
    int pos = atomicAdd(&cur[dst[e]], 1);
    pack[pos] = make_int2(src[e], __float_as_int(ef[e]));
}
// after CSR build: rowv[n] = row start, curv[n] = row end

// ---------------- per-layer coefficient precompute ----------------
template<int DIN, int DINP, int D>
__global__ void kCoef(const float* __restrict__ Wfc, const float* __restrict__ al,
                      const float* __restrict__ ar, const float* __restrict__ We,
                      const float* __restrict__ ae,
                      float* __restrict__ q, float* __restrict__ r, float* __restrict__ ce){
    int t = threadIdx.x;
    if (t < 3*DINP){
        int hd = t / DINP, k = t - hd*DINP;
        float qa = 0.f, ra = 0.f;
        if (k < DIN){
            for (int d = 0; d < D; ++d){
                float w = Wfc[k*3*D + hd*D + d];
                qa += w*al[hd*D+d];
                ra += w*ar[hd*D+d];
            }
        }
        q[t] = qa; r[t] = ra;
    }
    if (t < 3){
        float c = 0.f;
        for (int d = 0; d < D; ++d) c += We[t*D+d]*ae[t*D+d];
        ce[t] = c;
    }
}

// ---------------- layer-1 node-table prep ----------------
// ntab1 row (8 u32): [0..3]=8 halves (6 real + 2 zero), [4..6]=el0..2 f32, [7]=pad
__global__ void __launch_bounds__(256) kPrep1(const float* __restrict__ nf,
    const float* __restrict__ q1, const float* __restrict__ r1,
    u32* __restrict__ ntab1, float* __restrict__ er3a){
    int n = blockIdx.x*256 + threadIdx.x;
    if (n >= NN) return;
    float h[6];
    #pragma unroll
    for (int k = 0; k < 6; ++k) h[k] = nf[(size_t)n*6 + k];
    u32 row[8];
    __half2 p0 = __floats2half2_rn(h[0], h[1]);
    __half2 p1 = __floats2half2_rn(h[2], h[3]);
    __half2 p2 = __floats2half2_rn(h[4], h[5]);
    __half2 p3 = __floats2half2_rn(0.f, 0.f);
    row[0] = *(u32*)&p0; row[1] = *(u32*)&p1; row[2] = *(u32*)&p2; row[3] = *(u32*)&p3;
    #pragma unroll
    for (int hd = 0; hd < 3; ++hd){
        float el = 0.f, er = 0.f;
        #pragma unroll
        for (int k = 0; k < 6; ++k){ el += q1[hd*8+k]*h[k]; er += r1[hd*8+k]*h[k]; }
        row[4+hd] = __float_as_uint(el);
        er3a[(size_t)n*3+hd] = er;
    }
    row[7] = 0;
    uint4* rp = (uint4*)(ntab1 + (size_t)n*8);
    rp[0] = make_uint4(row[0],row[1],row[2],row[3]);
    rp[1] = make_uint4(row[4],row[5],row[6],row[7]);
}

// ---------------- fused layer: 4 lanes per node, all-register ----------------
// Edge loop (lane-strided over the node's contiguous CSR range): gather packed
// node row (h fp16 + el f32), ex = exp(lrelu(el + er + ce*ef)), accumulate
// s[3] + acc[3][DINP] in registers. Quad shfl_xor allreduce. Finalize lane-
// parallel: non-LAST emits only hmean (f32 + fp16 row + el/er for next layer);
// LAST emits fp16 h3 (head-strided dims keep all indexing static).
template<int DINP, int DINR, int D, bool LAST>
__global__ void __launch_bounds__(256) kFused(
    const int* __restrict__ rowv, const int* __restrict__ rend,
    const int2* __restrict__ pack, const u32* __restrict__ ntab,
    const float* __restrict__ er3, const float* __restrict__ cep,
    const float* __restrict__ hres, const float* __restrict__ Wfc,
    const float* __restrict__ Wres, const float* __restrict__ bias,
    float* __restrict__ hmean_o, u32* __restrict__ ntab_next,
    float* __restrict__ er3_next, const float* __restrict__ qnext,
    const float* __restrict__ rnext, u16* __restrict__ h3_o)
{
    constexpr int ROWU = (DINP/2 + 4) & ~1;   // u32/node-row: 8 (DINP=8), 12 (DINP=16)
    constexpr int CH = 3*DINP;
    const int t = blockIdx.x*256 + threadIdx.x;
    const int n = t >> 2, lane = t & 3;
    if (n >= NN) return;

    const int rs = rowv[n], re = rend[n];
    const float e0 = er3[(size_t)n*3+0], e1 = er3[(size_t)n*3+1], e2 = er3[(size_t)n*3+2];
    const float c0 = cep[0], c1 = cep[1], c2 = cep[2];

    float acc[CH];
    #pragma unroll
    for (int k = 0; k < CH; ++k) acc[k] = 0.f;
    float s0 = 0.f, s1 = 0.f, s2 = 0.f;

    for (int p = rs + lane; p < re; p += 4){
        int2 pk = pack[p];
        const float fv = __int_as_float(pk.y);
        const uint4* rp = (const uint4*)(ntab + (size_t)pk.x*ROWU);
        float hv[DINP];
        float el0, el1, el2;
        uint4 A = rp[0];
        if constexpr (DINP == 8){
            uint4 B = rp[1];
            float2 f;
            f = __half22float2(*(__half2*)&A.x); hv[0]=f.x; hv[1]=f.y;
            f = __half22float2(*(__half2*)&A.y); hv[2]=f.x; hv[3]=f.y;
            f = __half22float2(*(__half2*)&A.z); hv[4]=f.x; hv[5]=f.y;
            f = __half22float2(*(__half2*)&A.w); hv[6]=f.x; hv[7]=f.y;
            el0 = __uint_as_float(B.x); el1 = __uint_as_float(B.y); el2 = __uint_as_float(B.z);
        } else {
            uint4 B = rp[1];
            uint4 C = rp[2];
            float2 f;
            f = __half22float2(*(__half2*)&A.x); hv[0]=f.x; hv[1]=f.y;
            f = __half22float2(*(__half2*)&A.y); hv[2]=f.x; hv[3]=f.y;
            f = __half22float2(*(__half2*)&A.z); hv[4]=f.x; hv[5]=f.y;
            f = __half22float2(*(__half2*)&A.w); hv[6]=f.x; hv[7]=f.y;
            f = __half22float2(*(__half2*)&B.x); hv[8]=f.x; hv[9]=f.y;
            f = __half22float2(*(__half2*)&B.y); hv[10]=f.x; hv[11]=f.y;
            f = __half22float2(*(__half2*)&B.z); hv[12]=f.x; hv[13]=f.y;
            f = __half22float2(*(__half2*)&B.w); hv[14]=f.x; hv[15]=f.y;
            el0 = __uint_as_float(C.x); el1 = __uint_as_float(C.y); el2 = __uint_as_float(C.z);
        }
        float x0 = __expf(lrelu(el0 + e0 + c0*fv, 0.2f));
        float x1 = __expf(lrelu(el1 + e1 + c1*fv, 0.2f));
        float x2 = __expf(lrelu(el2 + e2 + c2*fv, 0.2f));
        s0 += x0; s1 += x1; s2 += x2;
        #pragma unroll
        for (int k = 0; k < DINP; ++k){
            acc[0*DINP+k] += x0*hv[k];
            acc[1*DINP+k] += x1*hv[k];
            acc[2*DINP+k] += x2*hv[k];
        }
    }

    // quad allreduce (xor 1,2 stays inside the 4-lane group)
    #pragma unroll
    for (int o = 1; o < 4; o <<= 1){
        s0 += __shfl_xor(s0, o);
        s1 += __shfl_xor(s1, o);
        s2 += __shfl_xor(s2, o);
        #pragma unroll
        for (int k = 0; k < CH; ++k) acc[k] += __shfl_xor(acc[k], o);
    }
    const float i0 = s0 > 0.f ? 1.f/s0 : 0.f;
    const float i1 = s1 > 0.f ? 1.f/s1 : 0.f;
    const float i2 = s2 > 0.f ? 1.f/s2 : 0.f;

    float hr[DINR];
    #pragma unroll
    for (int k = 0; k < DINR; ++k) hr[k] = hres[(size_t)n*DINR + k];

    if constexpr (!LAST){
        constexpr int DC = D/4;
        constexpr int ROWUn = (D/2 + 4) & ~1;
        float hm[DC];
        #pragma unroll
        for (int dd = 0; dd < DC; ++dd){
            int d = lane*DC + dd;
            float t0=0.f,t1=0.f,t2=0.f,r0=0.f,r1=0.f,r2=0.f;
            #pragma unroll
            for (int k = 0; k < DINR; ++k){
                const float* wf = Wfc  + k*3*D;
                const float* wr = Wres + k*3*D;
                t0 += acc[0*DINP+k]*wf[d];
                t1 += acc[1*DINP+k]*wf[D+d];
                t2 += acc[2*DINP+k]*wf[2*D+d];
                float hk = hr[k];
                r0 += hk*wr[d]; r1 += hk*wr[D+d]; r2 += hk*wr[2*D+d];
            }
            float o0 = i0*t0 + r0 + bias[d];
            float o1 = i1*t1 + r1 + bias[D+d];
            float o2 = i2*t2 + r2 + bias[2*D+d];
            hm[dd] = (o0 + o1 + o2) * (1.f/3.f);
        }
        #pragma unroll
        for (int dd = 0; dd < DC; ++dd)
            hmean_o[(size_t)n*D + lane*DC + dd] = hm[dd];
        #pragma unroll
        for (int w = 0; w < DC/2; ++w){
            __half2 hh = __floats2half2_rn(hm[2*w], hm[2*w+1]);
            ntab_next[(size_t)n*ROWUn + lane*(DC/2) + w] = *(u32*)&hh;
        }
        // next-layer el/er dots (partial per lane, quad allreduce)
        float pe[3], pr[3];
        #pragma unroll
        for (int hd = 0; hd < 3; ++hd){
            float a = 0.f, b_ = 0.f;
            #pragma unroll
            for (int dd = 0; dd < DC; ++dd){
                int d = lane*DC + dd;
                a  += qnext[hd*D + d]*hm[dd];
                b_ += rnext[hd*D + d]*hm[dd];
            }
            pe[hd] = a; pr[hd] = b_;
        }
        #pragma unroll
        for (int o = 1; o < 4; o <<= 1){
            #pragma unroll
            for (int hd = 0; hd < 3; ++hd){
                pe[hd] += __shfl_xor(pe[hd], o);
                pr[hd] += __shfl_xor(pr[hd], o);
            }
        }
        if (lane < 3){
            float ev = (lane==0) ? pe[0] : ((lane==1) ? pe[1] : pe[2]);
            float rv = (lane==0) ? pr[0] : ((lane==1) ? pr[1] : pr[2]);
            ntab_next[(size_t)n*ROWUn + D/2 + lane] = __float_as_uint(ev);
            er3_next[(size_t)n*3 + lane] = rv;
        }
    } else {
        // out dims head-strided: lane owns d in [lane*8, lane*8+8) of each head
        #pragma unroll
        for (int hd = 0; hd < 3; ++hd){
            float inv = (hd==0) ? i0 : ((hd==1) ? i1 : i2);
            u32 wpk[4];
            #pragma unroll
            for (int q2 = 0; q2 < 4; ++q2){
                float ov[2];
                #pragma unroll
                for (int u = 0; u < 2; ++u){
                    int j = hd*32 + lane*8 + q2*2 + u;
                    float tt = 0.f, rr = 0.f;
                    #pragma unroll
                    for (int k = 0; k < DINR; ++k){
                        tt += acc[hd*DINP+k]*Wfc[k*96 + j];
                        rr += hr[k]*Wres[k*96 + j];
                    }
                    ov[u] = inv*tt + rr + bias[j];
                }
                __half2 hh = __floats2half2_rn(ov[0], ov[1]);
                wpk[q2] = *(u32*)&hh;
            }
            *(uint4*)((u32*)h3_o + (size_t)n*48 + hd*16 + lane*4) =
                make_uint4(wpk[0], wpk[1], wpk[2], wpk[3]);
        }
    }
}

// ---------------- MLP head + global max (fp16 h3 input) ----------------
__global__ void __launch_bounds__(256) kHead(const u16* __restrict__ h3,
    const float* __restrict__ L1a_w, const float* __restrict__ L1a_b,
    const float* __restrict__ L1b_w, const float* __restrict__ L1b_b,
    const float* __restrict__ L1c_w, const float* __restrict__ L1c_b,
    const float* __restrict__ L2_w, const float* __restrict__ L2_b,
    float* __restrict__ out)
{
    __shared__ float red[256];
    int n = blockIdx.x*256 + threadIdx.x;
    float y = -INFINITY;
    if (n < NN) {
        const u16* p = h3 + (size_t)n*96;
        float acc = L2_b[0];
        #pragma unroll
        for (int h = 0; h < 3; ++h) {
            float hb[32];
            #pragma unroll
            for (int d = 0; d < 32; ++d) hb[d] = __half2float(*(const __half*)(p + h*32 + d));
            float x1[16];
            #pragma unroll
            for (int i = 0; i < 16; ++i) {
                float v = L1a_b[i];
                #pragma unroll
                for (int d = 0; d < 32; ++d) v += hb[d]*L1a_w[d*16+i];
                x1[i] = lrelu(v, 0.01f);
            }
            float x2[4];
            #pragma unroll
            for (int i = 0; i < 4; ++i) {
                float v = L1b_b[i];
                #pragma unroll
                for (int d = 0; d < 16; ++d) v += x1[d]*L1b_w[d*4+i];
                x2[i] = lrelu(v, 0.01f);
            }
            float v = L1c_b[0];
            #pragma unroll
            for (int d = 0; d < 4; ++d) v += x2[d]*L1c_w[d];
            acc += v*L2_w[h];
        }
        y = acc;
    }
    red[threadIdx.x] = y;
    __syncthreads();
    for (int o = 128; o > 0; o >>= 1) {
        if (threadIdx.x < o) red[threadIdx.x] = fmaxf(red[threadIdx.x], red[threadIdx.x+o]);
        __syncthreads();
    }
    if (threadIdx.x == 0) atomicMaxF(out, red[0]);
}

extern "C" void kernel_launch(void* const* d_in, const int* in_sizes, int n_in,
                              void* d_out, int out_size, void* d_ws, size_t ws_size,
                              hipStream_t stream) {
    const float* nf  = (const float*)d_in[0];
    const float* ef  = (const float*)d_in[1];
    const float* W1  = (const float*)d_in[2];
    const float* We1 = (const float*)d_in[3];
    const float* al1 = (const float*)d_in[4];
    const float* ar1 = (const float*)d_in[5];
    const float* ae1 = (const float*)d_in[6];
    const float* Wr1 = (const float*)d_in[7];
    const float* b1  = (const float*)d_in[8];
    const float* W2  = (const float*)d_in[9];
    const float* We2 = (const float*)d_in[10];
    const float* al2 = (const float*)d_in[11];
    const float* ar2 = (const float*)d_in[12];
    const float* ae2 = (const float*)d_in[13];
    const float* Wr2 = (const float*)d_in[14];
    const float* b2  = (const float*)d_in[15];
    const float* W3  = (const float*)d_in[16];
    const float* We3 = (const float*)d_in[17];
    const float* al3 = (const float*)d_in[18];
    const float* ar3 = (const float*)d_in[19];
    const float* ae3 = (const float*)d_in[20];
    const float* Wr3 = (const float*)d_in[21];
    const float* b3  = (const float*)d_in[22];
    const float* L1a_w = (const float*)d_in[23];
    const float* L1a_b = (const float*)d_in[24];
    const float* L1b_w = (const float*)d_in[25];
    const float* L1b_b = (const float*)d_in[26];
    const float* L1c_w = (const float*)d_in[27];
    const float* L1c_b = (const float*)d_in[28];
    const float* L2_w  = (const float*)d_in[29];
    const float* L2_b  = (const float*)d_in[30];
    const int* src = (const int*)d_in[31];
    const int* dst = (const int*)d_in[32];
    float* out = (float*)d_out;

    // ---- workspace layout ----
    float* ws = (float*)d_ws;
    u32* ntab1 = (u32*)ws;                        // [N,8]  u32
    u32* ntab2 = ntab1 + (size_t)NN*8;            // [N,8]  u32
    u32* ntab3 = ntab2 + (size_t)NN*8;            // [N,12] u32
    float* f   = (float*)(ntab3 + (size_t)NN*12);
    float* hm2  = f;  f += (size_t)NN*8;          // layer-2 residual input (f32)
    float* hm3  = f;  f += (size_t)NN*16;         // layer-3 residual input (f32)
    float* er3a = f;  f += (size_t)NN*3;
    float* er3b = f;  f += (size_t)NN*3;
    u16* h3g   = (u16*)f; f += (size_t)NN*48;     // [N,96] fp16
    float* coef = f;  f += 256;
    // coef: q1@0 r1@24 q2@48 r2@72 q3@96 r3@144 ce1@192 ce2@196 ce3@200
    int* deg  = (int*)f;
    int* rowv = deg + NN;
    int* curv = rowv + NN;
    int* bsum = curv + NN;
    int2* pack = (int2*)(bsum + 512);             // [E] {src, ef-bits}

    const int gN = (NN + 255)/256;
    const int gE = (NE + 255)/256;
    const int gT = (NN*4 + 255)/256;              // 4 lanes per node

    kInitOut<<<1,1,0,stream>>>(out);

    // ---- CSR build (by dst) ----
    hipMemsetAsync(deg, 0, NN*sizeof(int), stream);
    kHist<<<gE,256,0,stream>>>(dst, deg);
    kScan1<<<NB_SCAN,256,0,stream>>>(deg, rowv, bsum);
    kScan2<<<1,512,0,stream>>>(bsum);
    kScanFin<<<NB_SCAN,256,0,stream>>>(rowv, bsum, curv);
    kScatter<<<gE,256,0,stream>>>(src, dst, ef, curv, pack);

    // ---- coefficients ----
    kCoef<6,8,8>   <<<1,64,0,stream>>>(W1, al1, ar1, We1, ae1, coef+0,  coef+24,  coef+192);
    kCoef<8,8,16>  <<<1,64,0,stream>>>(W2, al2, ar2, We2, ae2, coef+48, coef+72,  coef+196);
    kCoef<16,16,32><<<1,64,0,stream>>>(W3, al3, ar3, We3, ae3, coef+96, coef+144, coef+200);

    // ---- layer-1 node table ----
    kPrep1<<<gN,256,0,stream>>>(nf, coef+0, coef+24, ntab1, er3a);

    // ---- Layer 1: DINP=8(pad 6), DINR=6, D=8 ----
    kFused<8,6,8,false><<<gT,256,0,stream>>>(rowv, curv, pack, ntab1, er3a, coef+192, nf,
        W1, Wr1, b1, hm2, ntab2, er3b, coef+48, coef+72, nullptr);

    // ---- Layer 2: DINP=8, DINR=8, D=16 ----
    kFused<8,8,16,false><<<gT,256,0,stream>>>(rowv, curv, pack, ntab2, er3b, coef+196, hm2,
        W2, Wr2, b2, hm3, ntab3, er3a, coef+96, coef+144, nullptr);

    // ---- Layer 3: DINP=16, DINR=16, D=32 ----
    kFused<16,16,32,true><<<gT,256,0,stream>>>(rowv, curv, pack, ntab3, er3a, coef+200, hm3,
        W3, Wr3, b3, nullptr, nullptr, nullptr, nullptr, nullptr, h3g);

    // ---- MLP head + global max ----
    kHead<<<gN,256,0,stream>>>(h3g, L1a_w, L1a_b, L1b_w, L1b_b, L1c_w, L1c_b, L2_w, L2_b, out);
}